// Round 2
// baseline (5599.468 us; speedup 1.0000x reference)
//
#include <hip/hip_runtime.h>

typedef _Float16 h16;
typedef _Float16 h16x4 __attribute__((ext_vector_type(4)));
typedef _Float16 h16x8 __attribute__((ext_vector_type(8)));
typedef float f32x4 __attribute__((ext_vector_type(4)));
typedef unsigned short u16;

__device__ __forceinline__ f32x4 mfma16(h16x8 a, h16x8 b, f32x4 c) {
  return __builtin_amdgcn_mfma_f32_16x16x32_f16(a, b, c, 0, 0, 0);
}

// ---------------- RMSNorm: f32 [2048][4096] -> f16 ----------------
__global__ __launch_bounds__(256) void rmsnorm_k(
    const float* __restrict__ x, const float* __restrict__ w, h16* __restrict__ out) {
  const int row = blockIdx.x, t = threadIdx.x;
  const float* xr = x + (size_t)row * 4096;
  float4 v[4];
  float ss = 0.f;
#pragma unroll
  for (int j = 0; j < 4; j++) {
    v[j] = *(const float4*)(xr + 4 * t + 1024 * j);
    ss += v[j].x * v[j].x + v[j].y * v[j].y + v[j].z * v[j].z + v[j].w * v[j].w;
  }
#pragma unroll
  for (int off = 1; off < 64; off <<= 1) ss += __shfl_xor(ss, off, 64);
  __shared__ float red[4];
  if ((t & 63) == 0) red[t >> 6] = ss;
  __syncthreads();
  float scale = rsqrtf((red[0] + red[1] + red[2] + red[3]) * (1.f / 4096.f) + 1e-6f);
  h16* orow = out + (size_t)row * 4096;
#pragma unroll
  for (int j = 0; j < 4; j++) {
    float4 wv = *(const float4*)(w + 4 * t + 1024 * j);
    h16x4 o;
    o[0] = (h16)(v[j].x * scale * wv.x);
    o[1] = (h16)(v[j].y * scale * wv.y);
    o[2] = (h16)(v[j].z * scale * wv.z);
    o[3] = (h16)(v[j].w * scale * wv.w);
    *(h16x4*)(orow + 4 * t + 1024 * j) = o;
  }
}

// ---------------- GEMM: C[M][N] = A(f16 [M][K]) * W(f32 [K][N]) ----------------
// 128x128 tile, BK=64, 4 waves of 64x64, XOR-swizzled LDS (chunk ^= row&7).
// EPI: 0 -> f32 out, 1 -> f16 out, 2 -> f32 out = resid + acc
template <int EPI>
__global__ __launch_bounds__(256, 2) void gemm_k(
    const h16* __restrict__ A, const float* __restrict__ W,
    float* __restrict__ outF, h16* __restrict__ outH,
    const float* __restrict__ resid, int N, int K) {
  __shared__ u16 sA[128 * 64];
  __shared__ u16 sB[128 * 64];
  const int tid = threadIdx.x, lane = tid & 63;
  const int wv = tid >> 6, wr = wv >> 1, wc = wv & 1;
  const int g = lane >> 4, lr = lane & 15;
  const int m0 = blockIdx.y << 7, n0 = blockIdx.x << 7;

  f32x4 acc[4][4];
#pragma unroll
  for (int i = 0; i < 4; i++)
#pragma unroll
    for (int j = 0; j < 4; j++) acc[i][j] = {0.f, 0.f, 0.f, 0.f};

  const int nB = tid & 127, kg0 = tid >> 7;
  const int nkt = K >> 6;
  for (int kt = 0; kt < nkt; ++kt) {
    __syncthreads();
    // stage A tile: [128 m][64 k] f16, direct copy, swizzled b128 writes
#pragma unroll
    for (int i = 0; i < 4; i++) {
      int c = tid + (i << 8);
      int m = c >> 3, kc = c & 7;
      uint4 d = *(const uint4*)(A + (size_t)(m0 + m) * K + (kt << 6) + (kc << 3));
      *(uint4*)((char*)sA + m * 128 + ((kc ^ (m & 7)) << 4)) = d;
    }
    // stage B tile transposed: [128 n][64 k] f16 from f32 W rows (8 strided
    // coalesced scalar loads per chunk -> cvt -> one swizzled b128 write)
#pragma unroll
    for (int i = 0; i < 4; i++) {
      int kg = kg0 + 2 * i;
      const float* wp = W + (size_t)((kt << 6) + (kg << 3)) * N + n0 + nB;
      h16x8 hv;
#pragma unroll
      for (int u = 0; u < 8; u++) hv[u] = (h16)wp[(size_t)u * N];
      *(h16x8*)((char*)sB + nB * 128 + ((kg ^ (nB & 7)) << 4)) = hv;
    }
    __syncthreads();
#pragma unroll
    for (int ks = 0; ks < 2; ++ks) {
      h16x8 av[4], bv[4];
#pragma unroll
      for (int f = 0; f < 4; f++) {
        int row = (wr << 6) + (f << 4) + lr;
        int ch = (ks << 2) + g;
        av[f] = *(const h16x8*)((char*)sA + row * 128 + ((ch ^ (row & 7)) << 4));
        int col = (wc << 6) + (f << 4) + lr;
        bv[f] = *(const h16x8*)((char*)sB + col * 128 + ((ch ^ (col & 7)) << 4));
      }
#pragma unroll
      for (int fi = 0; fi < 4; fi++)
#pragma unroll
        for (int fj = 0; fj < 4; fj++)
          acc[fi][fj] = mfma16(av[fi], bv[fj], acc[fi][fj]);
    }
  }
  // epilogue; C/D layout: col=lane&15, row=(lane>>4)*4+r (m89-verified)
#pragma unroll
  for (int fi = 0; fi < 4; fi++) {
    const int row = m0 + (wr << 6) + (fi << 4) + (g << 2);
#pragma unroll
    for (int fj = 0; fj < 4; fj++) {
      const int col = n0 + (wc << 6) + (fj << 4) + lr;
#pragma unroll
      for (int r = 0; r < 4; r++) {
        size_t idx = (size_t)(row + r) * N + col;
        float vl = acc[fi][fj][r];
        if constexpr (EPI == 0) outF[idx] = vl;
        else if constexpr (EPI == 1) outH[idx] = (h16)vl;
        else outF[idx] = resid[idx] + vl;
      }
    }
  }
}

// ---------------- RoPE on Q (f16 in/out, out-of-place) ----------------
__global__ __launch_bounds__(256) void rope_q_k(
    const h16* __restrict__ qin, const float* __restrict__ freqs, h16* __restrict__ qout) {
  const int row = blockIdx.x, t = threadIdx.x;
#pragma unroll
  for (int it = 0; it < 8; ++it) {
    int pid = t + 256 * it;          // 0..2047 : head*64 + pair
    int head = pid >> 6, pp = pid & 63;
    size_t idx = (size_t)row * 4096 + head * 128 + 2 * pp;
    float x0 = (float)qin[idx], x1 = (float)qin[idx + 1];
    float cs = freqs[row * 128 + 2 * pp], sn = freqs[row * 128 + 2 * pp + 1];
    qout[idx] = (h16)(x0 * cs - x1 * sn);
    qout[idx + 1] = (h16)(x0 * sn + x1 * cs);
  }
}

// ---------------- build new cache: f32 outs + f16 K [kvh][r][d] + f16 V^T [kvh][d][r]
__global__ __launch_bounds__(256) void cache_build_k(
    const float* __restrict__ oldK, const float* __restrict__ oldV,
    const float* __restrict__ kraw, const float* __restrict__ vraw,
    const float* __restrict__ freqs,
    float* __restrict__ outK, float* __restrict__ outV,
    h16* __restrict__ Kf, h16* __restrict__ Vt) {
  const int rt = blockIdx.x, kvh = blockIdx.y;
  const int r0 = rt * 64, tid = threadIdx.x;
  __shared__ u16 vtile[64][128];
#pragma unroll
  for (int it = 0; it < 16; ++it) {
    int s = tid + 256 * it;
    int rr = s >> 6, pp = s & 63;
    int r = r0 + rr;
    float k0, k1, v0, v1;
    if (r < 2048) {
      const float* kp = oldK + (size_t)(r + 2048) * 1024 + kvh * 128 + 2 * pp;
      k0 = kp[0]; k1 = kp[1];
      const float* vp = oldV + (size_t)(r + 2048) * 1024 + kvh * 128 + 2 * pp;
      v0 = vp[0]; v1 = vp[1];
    } else {
      int tpos = r - 2048;
      const float* kp = kraw + (size_t)tpos * 1024 + kvh * 128 + 2 * pp;
      float x0 = kp[0], x1 = kp[1];
      float cs = freqs[tpos * 128 + 2 * pp], sn = freqs[tpos * 128 + 2 * pp + 1];
      k0 = x0 * cs - x1 * sn;
      k1 = x0 * sn + x1 * cs;
      const float* vp = vraw + (size_t)tpos * 1024 + kvh * 128 + 2 * pp;
      v0 = vp[0]; v1 = vp[1];
    }
    size_t oidx = (size_t)r * 1024 + kvh * 128 + 2 * pp;
    outK[oidx] = k0; outK[oidx + 1] = k1;
    outV[oidx] = v0; outV[oidx + 1] = v1;
    size_t kfi = (size_t)kvh * 524288 + (size_t)r * 128 + 2 * pp;
    Kf[kfi] = (h16)k0; Kf[kfi + 1] = (h16)k1;
    h16 h0 = (h16)v0, h1 = (h16)v1;
    vtile[rr][2 * pp] = __builtin_bit_cast(u16, h0);
    vtile[rr][2 * pp + 1] = __builtin_bit_cast(u16, h1);
  }
  __syncthreads();
#pragma unroll
  for (int it = 0; it < 4; ++it) {
    int c = tid + 256 * it;
    int d = c >> 3, rg = c & 7;
    u16 tmp[8];
#pragma unroll
    for (int u = 0; u < 8; u++) tmp[u] = vtile[rg * 8 + u][d];
    *(uint4*)((u16*)Vt + (size_t)kvh * 524288 + (size_t)d * 4096 + r0 + rg * 8) =
        *(uint4*)tmp;
  }
}

// ---------------- flash attention (GQA, causal-offset mask j <= 2048+q) ----------
__global__ __launch_bounds__(256) void attn_k(
    const h16* __restrict__ Q, const h16* __restrict__ Kf,
    const h16* __restrict__ Vt, h16* __restrict__ O) {
  __shared__ u16 sK[64 * 128];   // [j][d] swizzled
  __shared__ u16 sV[128 * 64];   // [d][j] swizzled
  __shared__ u16 sP[4 * 16 * 64];
  const int qt = blockIdx.x, h = blockIdx.y;
  const int q0 = qt * 64, kvh = h >> 2;
  const int tid = threadIdx.x, lane = tid & 63, w = tid >> 6;
  const int g = lane >> 4, lr = lane & 15;

  h16x8 qv[4];
  {
    const h16* qp = Q + (size_t)(q0 + w * 16 + lr) * 4096 + h * 128;
#pragma unroll
    for (int ks = 0; ks < 4; ++ks) qv[ks] = *(const h16x8*)(qp + ks * 32 + g * 8);
  }
  f32x4 oacc[8];
#pragma unroll
  for (int d = 0; d < 8; ++d) oacc[d] = {0.f, 0.f, 0.f, 0.f};
  float mrow[4] = {-1e30f, -1e30f, -1e30f, -1e30f};
  float lrow[4] = {0.f, 0.f, 0.f, 0.f};

  const h16* Kb = Kf + (size_t)kvh * 524288;
  const h16* Vb = Vt + (size_t)kvh * 524288;
  const int ntiles = qt + 33;
  const float sc = 0.08838834764831845f;  // 1/sqrt(128)

  for (int jt = 0; jt < ntiles; ++jt) {
    const int j0 = jt * 64;
    __syncthreads();
#pragma unroll
    for (int i = 0; i < 4; i++) {
      int c = tid + (i << 8);
      int j = c >> 4, dc = c & 15;
      uint4 dat = *(const uint4*)(Kb + (size_t)(j0 + j) * 128 + dc * 8);
      *(uint4*)((char*)sK + j * 256 + ((dc ^ (j & 7)) << 4)) = dat;
    }
#pragma unroll
    for (int i = 0; i < 4; i++) {
      int c = tid + (i << 8);
      int d = c >> 3, jc = c & 7;
      uint4 dat = *(const uint4*)(Vb + (size_t)d * 4096 + j0 + jc * 8);
      *(uint4*)((char*)sV + d * 128 + ((jc ^ (d & 7)) << 4)) = dat;
    }
    __syncthreads();

    f32x4 sj[4];
#pragma unroll
    for (int jf = 0; jf < 4; jf++) {
      f32x4 s = {0.f, 0.f, 0.f, 0.f};
      const int j = jf * 16 + lr;
#pragma unroll
      for (int ks = 0; ks < 4; ks++) {
        const int ch = ks * 4 + g;
        h16x8 kb = *(const h16x8*)((char*)sK + j * 256 + ((ch ^ (j & 7)) << 4));
        s = mfma16(qv[ks], kb, s);
      }
      sj[jf] = s;
    }
    const bool maskt = (jt == ntiles - 1);
    float pm[4] = {-1e30f, -1e30f, -1e30f, -1e30f};
#pragma unroll
    for (int jf = 0; jf < 4; jf++)
#pragma unroll
      for (int r = 0; r < 4; r++) {
        float val = sj[jf][r] * sc;
        if (maskt) {
          int jg = j0 + jf * 16 + lr;
          int qg = q0 + w * 16 + g * 4 + r;
          if (jg > 2048 + qg) val = -1e30f;
        }
        sj[jf][r] = val;
        pm[r] = fmaxf(pm[r], val);
      }
#pragma unroll
    for (int r = 0; r < 4; r++)
#pragma unroll
      for (int off = 1; off < 16; off <<= 1)
        pm[r] = fmaxf(pm[r], __shfl_xor(pm[r], off, 16));
    float al[4], rs[4];
#pragma unroll
    for (int r = 0; r < 4; r++) {
      float mn = fmaxf(mrow[r], pm[r]);
      al[r] = __expf(mrow[r] - mn);
      mrow[r] = mn;
      rs[r] = 0.f;
    }
#pragma unroll
    for (int jf = 0; jf < 4; jf++)
#pragma unroll
      for (int r = 0; r < 4; r++) {
        float p = __expf(sj[jf][r] - mrow[r]);
        rs[r] += p;
        int qrow = g * 4 + r;
        int j = jf * 16 + lr;
        int ch = j >> 3;
        *(h16*)((char*)sP + w * 2048 + qrow * 128 + ((ch ^ (qrow & 7)) << 4) +
                (j & 7) * 2) = (h16)p;
      }
#pragma unroll
    for (int r = 0; r < 4; r++) {
#pragma unroll
      for (int off = 1; off < 16; off <<= 1) rs[r] += __shfl_xor(rs[r], off, 16);
      lrow[r] = lrow[r] * al[r] + rs[r];
    }
#pragma unroll
    for (int d = 0; d < 8; ++d)
#pragma unroll
      for (int r = 0; r < 4; r++) oacc[d][r] *= al[r];
    // PV: P (wave-private LDS) as A-fragments, V^T as B-fragments
#pragma unroll
    for (int ks = 0; ks < 2; ++ks) {
      const int ch = ks * 4 + g;
      h16x8 pa = *(const h16x8*)((char*)sP + w * 2048 + lr * 128 +
                                 ((ch ^ (lr & 7)) << 4));
#pragma unroll
      for (int df = 0; df < 8; ++df) {
        const int d = df * 16 + lr;
        h16x8 vb = *(const h16x8*)((char*)sV + d * 128 + ((ch ^ (d & 7)) << 4));
        oacc[df] = mfma16(pa, vb, oacc[df]);
      }
    }
  }
  h16* Op = O + (size_t)(q0 + w * 16 + g * 4) * 4096 + h * 128 + lr;
#pragma unroll
  for (int df = 0; df < 8; ++df)
#pragma unroll
    for (int r = 0; r < 4; r++) {
      float val = oacc[df][r] / lrow[r];
      Op[(size_t)r * 4096 + df * 16] = (h16)val;
    }
}

// ---------------- SwiGLU elementwise: g = silu(u) * v (f16, in-place safe) ----
__global__ __launch_bounds__(256) void silumul_k(
    const h16* __restrict__ u, const h16* __restrict__ v, h16* __restrict__ g, int n8) {
  int i = blockIdx.x * blockDim.x + threadIdx.x;
  const int stride = gridDim.x * blockDim.x;
  for (; i < n8; i += stride) {
    h16x8 uu = *(const h16x8*)(u + (size_t)i * 8);
    h16x8 vv = *(const h16x8*)(v + (size_t)i * 8);
    h16x8 oo;
#pragma unroll
    for (int j = 0; j < 8; j++) {
      float a = (float)uu[j], b = (float)vv[j];
      float s = a / (1.f + __expf(-a));
      oo[j] = (h16)(s * b);
    }
    *(h16x8*)(g + (size_t)i * 8) = oo;
  }
}

extern "C" void kernel_launch(void* const* d_in, const int* in_sizes, int n_in,
                              void* d_out, int out_size, void* d_ws, size_t ws_size,
                              hipStream_t stream) {
  const float* x = (const float*)d_in[0];
  const float* freqs = (const float*)d_in[2];
  const float* oldK = (const float*)d_in[3];
  const float* oldV = (const float*)d_in[4];
  const float* wq = (const float*)d_in[5];
  const float* wk = (const float*)d_in[6];
  const float* wvp = (const float*)d_in[7];
  const float* wo = (const float*)d_in[8];
  const float* w1 = (const float*)d_in[9];
  const float* w2 = (const float*)d_in[10];
  const float* w3 = (const float*)d_in[11];
  const float* anw = (const float*)d_in[12];
  const float* fnw = (const float*)d_in[13];
  float* out = (float*)d_out;
  float* outK = out + 8388608;
  float* outV = out + 12582912;

  char* ws = (char*)d_ws;
  // phased layout (peak 168 MiB)
  h16* xn = (h16*)(ws + 0);               // 16 MiB  f16 [2048][4096], also hn
  h16* qraw = (h16*)(ws + 16777216);      // 16 MiB
  float* kraw = (float*)(ws + 33554432);  // 8 MiB  f32 [2048][1024]
  float* vraw = (float*)(ws + 41943040);  // 8 MiB
  h16* qrope = (h16*)(ws + 50331648);     // 16 MiB
  h16* kf = (h16*)(ws + 67108864);        // 8 MiB  f16 [8][4096][128]
  h16* vt = (h16*)(ws + 75497472);        // 8 MiB  f16 [8][128][4096]
  h16* attn = (h16*)(ws + 16777216);      // reuse qraw slot (dead by then)
  h16* ub = (h16*)(ws + 16777216);        // 56 MiB span (all prior dead by FFN)
  float* hbuf = (float*)(ws + 83886080);  // 32 MiB f32 [2048][4096]
  h16* vb = (h16*)(ws + 117440512);       // 56 MiB
  h16* gb = ub;                           // in-place silu (elementwise, safe)

  rmsnorm_k<<<2048, 256, 0, stream>>>(x, anw, xn);
  gemm_k<1><<<dim3(32, 16), 256, 0, stream>>>(xn, wq, nullptr, qraw, nullptr, 4096, 4096);
  gemm_k<0><<<dim3(8, 16), 256, 0, stream>>>(xn, wk, kraw, nullptr, nullptr, 1024, 4096);
  gemm_k<0><<<dim3(8, 16), 256, 0, stream>>>(xn, wvp, vraw, nullptr, nullptr, 1024, 4096);
  rope_q_k<<<2048, 256, 0, stream>>>(qraw, freqs, qrope);
  cache_build_k<<<dim3(64, 8), 256, 0, stream>>>(oldK, oldV, kraw, vraw, freqs,
                                                 outK, outV, kf, vt);
  attn_k<<<dim3(32, 32), 256, 0, stream>>>(qrope, kf, vt, attn);
  gemm_k<2><<<dim3(32, 16), 256, 0, stream>>>(attn, wo, hbuf, nullptr, x, 4096, 4096);
  rmsnorm_k<<<2048, 256, 0, stream>>>(hbuf, fnw, xn);
  gemm_k<1><<<dim3(112, 16), 256, 0, stream>>>(xn, w1, nullptr, ub, nullptr, 14336, 4096);
  gemm_k<1><<<dim3(112, 16), 256, 0, stream>>>(xn, w3, nullptr, vb, nullptr, 14336, 4096);
  silumul_k<<<2048, 256, 0, stream>>>(ub, vb, gb, 3670016);
  gemm_k<2><<<dim3(32, 16), 256, 0, stream>>>(gb, w2, out, nullptr, hbuf, 4096, 14336);
}

// Round 3
// 1843.233 us; speedup vs baseline: 3.0379x; 3.0379x over previous
//
#include <hip/hip_runtime.h>

typedef _Float16 h16;
typedef _Float16 h16x4 __attribute__((ext_vector_type(4)));
typedef _Float16 h16x8 __attribute__((ext_vector_type(8)));
typedef float f32x4 __attribute__((ext_vector_type(4)));
typedef unsigned short u16;

__device__ __forceinline__ f32x4 mfma16(h16x8 a, h16x8 b, f32x4 c) {
  return __builtin_amdgcn_mfma_f32_16x16x32_f16(a, b, c, 0, 0, 0);
}

typedef const __attribute__((address_space(1))) void* gas_p;
typedef __attribute__((address_space(3))) void* las_p;
__device__ __forceinline__ void ldscp16(const void* g, void* l) {
  __builtin_amdgcn_global_load_lds((gas_p)g, (las_p)l, 16, 0, 0);
}

// ---------------- RMSNorm: f32 [2048][4096] -> f16 ----------------
__global__ __launch_bounds__(256) void rmsnorm_k(
    const float* __restrict__ x, const float* __restrict__ w, h16* __restrict__ out) {
  const int row = blockIdx.x, t = threadIdx.x;
  const float* xr = x + (size_t)row * 4096;
  float4 v[4];
  float ss = 0.f;
#pragma unroll
  for (int j = 0; j < 4; j++) {
    v[j] = *(const float4*)(xr + 4 * t + 1024 * j);
    ss += v[j].x * v[j].x + v[j].y * v[j].y + v[j].z * v[j].z + v[j].w * v[j].w;
  }
#pragma unroll
  for (int off = 1; off < 64; off <<= 1) ss += __shfl_xor(ss, off, 64);
  __shared__ float red[4];
  if ((t & 63) == 0) red[t >> 6] = ss;
  __syncthreads();
  float scale = rsqrtf((red[0] + red[1] + red[2] + red[3]) * (1.f / 4096.f) + 1e-6f);
  h16* orow = out + (size_t)row * 4096;
#pragma unroll
  for (int j = 0; j < 4; j++) {
    float4 wv = *(const float4*)(w + 4 * t + 1024 * j);
    h16x4 o;
    o[0] = (h16)(v[j].x * scale * wv.x);
    o[1] = (h16)(v[j].y * scale * wv.y);
    o[2] = (h16)(v[j].z * scale * wv.z);
    o[3] = (h16)(v[j].w * scale * wv.w);
    *(h16x4*)(orow + 4 * t + 1024 * j) = o;
  }
}

// ------- weight convert: f32 W[k0..+64kt rows][rowN] subblock -> f16 tiled+swizzled
// tile (b, kt): 128 n x 64 k, stored as the exact 16 KB LDS image the GEMM wants:
// u16 index = m*64 + ((kc ^ (m&7))<<3) + e   (k = kt*64 + kc*8 + e, m = n in tile)
__global__ __launch_bounds__(256) void convw_k(
    const float* __restrict__ W, h16* __restrict__ out, int rowN, int ktiles) {
  __shared__ u16 timg[8192];
  const int t = threadIdx.x, b = blockIdx.x, kt = blockIdx.y;
  const float* src = W + (size_t)(kt * 64) * rowN + b * 128;
#pragma unroll
  for (int i = 0; i < 8; i++) {
    int c = t + (i << 8);
    int krow = c >> 5, nc = (c & 31) << 2;
    float4 v = *(const float4*)(src + (size_t)krow * rowN + nc);
    int kc = krow >> 3, e = krow & 7;
    float vals[4] = {v.x, v.y, v.z, v.w};
#pragma unroll
    for (int j = 0; j < 4; j++) {
      int m = nc + j;
      h16 hv = (h16)vals[j];
      timg[(m << 6) + ((kc ^ (m & 7)) << 3) + e] = __builtin_bit_cast(u16, hv);
    }
  }
  __syncthreads();
  uint4* dst = (uint4*)(out + ((size_t)(b * ktiles + kt) << 13));
  const uint4* s4 = (const uint4*)timg;
#pragma unroll
  for (int i = 0; i < 4; i++) dst[t + (i << 8)] = s4[t + (i << 8)];
}

// ---------------- GEMM: C[M][N'] = A(f16, lda) * Wt(pre-tiled f16) ----------------
// 128x128 tile, BK=64, 4 waves of 64x64. global_load_lds staging, swizzled reads.
// EPI: 0 f32 out; 1 f16 out; 2 f32 out = resid + acc; 3 f16 out = silu(uin)*acc;
//      4 f32 out += acc
template <int EPI>
__global__ __launch_bounds__(256, 2) void gemm_k(
    const h16* __restrict__ A, const h16* __restrict__ Wt,
    float* outF, h16* outH, const float* resid, const h16* uin,
    int K, int lda, int ldo, int no0) {
  __shared__ u16 sA[8192];
  __shared__ u16 sB[8192];
  const int tid = threadIdx.x, lane = tid & 63;
  const int wv = tid >> 6, wr = wv >> 1, wc = wv & 1;
  const int g = lane >> 4, lr = lane & 15;
  const int m0 = blockIdx.y << 7, n0 = blockIdx.x << 7;
  const int r8 = lane >> 3, ch = lane & 7;
  const int ktiles = K >> 6;

  f32x4 acc[4][4];
#pragma unroll
  for (int i = 0; i < 4; i++)
#pragma unroll
    for (int j = 0; j < 4; j++) acc[i][j] = {0.f, 0.f, 0.f, 0.f};

  // per-lane staging sources (A: pre-swizzled chunk within row; B: linear image)
  const h16* gA = A + (size_t)(m0 + wv * 8 + r8) * lda + ((ch ^ r8) << 3);
  const h16* gB = Wt + ((size_t)blockIdx.x * ktiles << 13) + (wv << 9) + (lane << 3);
  char* lA = (char*)sA + (wv << 10);
  char* lB = (char*)sB + (wv << 10);

  for (int kt = 0; kt < ktiles; ++kt) {
    __syncthreads();
#pragma unroll
    for (int i = 0; i < 4; i++) {
      ldscp16(gA + (size_t)i * 32 * lda, lA + i * 4096);
      ldscp16(gB + i * 2048, lB + i * 4096);
    }
    gA += 64;
    gB += 8192;
    __syncthreads();
#pragma unroll
    for (int ks = 0; ks < 2; ++ks) {
      h16x8 av[4], bv[4];
#pragma unroll
      for (int f = 0; f < 4; f++) {
        int row = (wr << 6) + (f << 4) + lr;
        int cc = (ks << 2) + g;
        av[f] = *(const h16x8*)((char*)sA + row * 128 + ((cc ^ (row & 7)) << 4));
        int col = (wc << 6) + (f << 4) + lr;
        bv[f] = *(const h16x8*)((char*)sB + col * 128 + ((cc ^ (col & 7)) << 4));
      }
#pragma unroll
      for (int fi = 0; fi < 4; fi++)
#pragma unroll
        for (int fj = 0; fj < 4; fj++)
          acc[fi][fj] = mfma16(av[fi], bv[fj], acc[fi][fj]);
    }
  }
  // epilogue; C/D layout: col=lane&15, row=(lane>>4)*4+r (m89-verified)
#pragma unroll
  for (int fi = 0; fi < 4; fi++) {
    const int row = m0 + (wr << 6) + (fi << 4) + (g << 2);
#pragma unroll
    for (int fj = 0; fj < 4; fj++) {
      const int col = no0 + n0 + (wc << 6) + (fj << 4) + lr;
#pragma unroll
      for (int r = 0; r < 4; r++) {
        size_t idx = (size_t)(row + r) * ldo + col;
        float vl = acc[fi][fj][r];
        if constexpr (EPI == 0) outF[idx] = vl;
        else if constexpr (EPI == 1) outH[idx] = (h16)vl;
        else if constexpr (EPI == 2) outF[idx] = resid[idx] + vl;
        else if constexpr (EPI == 3) {
          float u = (float)uin[idx];
          outH[idx] = (h16)((u / (1.f + __expf(-u))) * vl);
        } else outF[idx] = outF[idx] + vl;
      }
    }
  }
}

// ---------------- RoPE on Q (f16, in-place safe: per-element) ----------------
__global__ __launch_bounds__(256) void rope_q_k(
    const h16* __restrict__ qin, const float* __restrict__ freqs, h16* qout) {
  const int row = blockIdx.x, t = threadIdx.x;
#pragma unroll
  for (int it = 0; it < 8; ++it) {
    int pid = t + 256 * it;
    int head = pid >> 6, pp = pid & 63;
    size_t idx = (size_t)row * 4096 + head * 128 + 2 * pp;
    float x0 = (float)qin[idx], x1 = (float)qin[idx + 1];
    float cs = freqs[row * 128 + 2 * pp], sn = freqs[row * 128 + 2 * pp + 1];
    qout[idx] = (h16)(x0 * cs - x1 * sn);
    qout[idx + 1] = (h16)(x0 * sn + x1 * cs);
  }
}

// ------- build new cache: f32 outs + f16 K [kvh][r][d] + f16 V^T [kvh][d][r] -------
// kvraw: f32 [2048][2048], cols 0..1023 = K, 1024..2047 = V
__global__ __launch_bounds__(256) void cache_build_k(
    const float* __restrict__ oldK, const float* __restrict__ oldV,
    const float* __restrict__ kvraw, const float* __restrict__ freqs,
    float* __restrict__ outK, float* __restrict__ outV,
    h16* __restrict__ Kf, h16* __restrict__ Vt) {
  const int rt = blockIdx.x, kvh = blockIdx.y;
  const int r0 = rt * 64, tid = threadIdx.x;
  __shared__ u16 vtile[64][128];
#pragma unroll
  for (int it = 0; it < 16; ++it) {
    int s = tid + 256 * it;
    int rr = s >> 6, pp = s & 63;
    int r = r0 + rr;
    float k0, k1, v0, v1;
    if (r < 2048) {
      const float* kp = oldK + (size_t)(r + 2048) * 1024 + kvh * 128 + 2 * pp;
      k0 = kp[0]; k1 = kp[1];
      const float* vp = oldV + (size_t)(r + 2048) * 1024 + kvh * 128 + 2 * pp;
      v0 = vp[0]; v1 = vp[1];
    } else {
      int tpos = r - 2048;
      const float* kp = kvraw + (size_t)tpos * 2048 + kvh * 128 + 2 * pp;
      float x0 = kp[0], x1 = kp[1];
      float cs = freqs[tpos * 128 + 2 * pp], sn = freqs[tpos * 128 + 2 * pp + 1];
      k0 = x0 * cs - x1 * sn;
      k1 = x0 * sn + x1 * cs;
      const float* vp = kvraw + (size_t)tpos * 2048 + 1024 + kvh * 128 + 2 * pp;
      v0 = vp[0]; v1 = vp[1];
    }
    size_t oidx = (size_t)r * 1024 + kvh * 128 + 2 * pp;
    outK[oidx] = k0; outK[oidx + 1] = k1;
    outV[oidx] = v0; outV[oidx + 1] = v1;
    size_t kfi = (size_t)kvh * 524288 + (size_t)r * 128 + 2 * pp;
    Kf[kfi] = (h16)k0; Kf[kfi + 1] = (h16)k1;
    h16 h0 = (h16)v0, h1 = (h16)v1;
    vtile[rr][2 * pp] = __builtin_bit_cast(u16, h0);
    vtile[rr][2 * pp + 1] = __builtin_bit_cast(u16, h1);
  }
  __syncthreads();
#pragma unroll
  for (int it = 0; it < 4; ++it) {
    int c = tid + 256 * it;
    int d = c >> 3, rg = c & 7;
    u16 tmp[8];
#pragma unroll
    for (int u = 0; u < 8; u++) tmp[u] = vtile[rg * 8 + u][d];
    *(uint4*)((u16*)Vt + (size_t)kvh * 524288 + (size_t)d * 4096 + r0 + rg * 8) =
        *(uint4*)tmp;
  }
}

// ---------------- flash attention (GQA, causal-offset mask j <= 2048+q) ----------
__global__ __launch_bounds__(256) void attn_k(
    const h16* __restrict__ Q, const h16* __restrict__ Kf,
    const h16* __restrict__ Vt, h16* __restrict__ O) {
  __shared__ u16 sK[64 * 128];
  __shared__ u16 sV[128 * 64];
  __shared__ u16 sP[4 * 16 * 64];
  const int qt = blockIdx.x, h = blockIdx.y;
  const int q0 = qt * 64, kvh = h >> 2;
  const int tid = threadIdx.x, lane = tid & 63, w = tid >> 6;
  const int g = lane >> 4, lr = lane & 15;

  h16x8 qv[4];
  {
    const h16* qp = Q + (size_t)(q0 + w * 16 + lr) * 4096 + h * 128;
#pragma unroll
    for (int ks = 0; ks < 4; ++ks) qv[ks] = *(const h16x8*)(qp + ks * 32 + g * 8);
  }
  f32x4 oacc[8];
#pragma unroll
  for (int d = 0; d < 8; ++d) oacc[d] = {0.f, 0.f, 0.f, 0.f};
  float mrow[4] = {-1e30f, -1e30f, -1e30f, -1e30f};
  float lrow[4] = {0.f, 0.f, 0.f, 0.f};

  const h16* Kb = Kf + (size_t)kvh * 524288;
  const h16* Vb = Vt + (size_t)kvh * 524288;
  const int ntiles = qt + 33;
  const float sc = 0.08838834764831845f;

  for (int jt = 0; jt < ntiles; ++jt) {
    const int j0 = jt * 64;
    __syncthreads();
#pragma unroll
    for (int i = 0; i < 4; i++) {
      int c = tid + (i << 8);
      int j = c >> 4, dc = c & 15;
      uint4 dat = *(const uint4*)(Kb + (size_t)(j0 + j) * 128 + dc * 8);
      *(uint4*)((char*)sK + j * 256 + ((dc ^ (j & 7)) << 4)) = dat;
    }
#pragma unroll
    for (int i = 0; i < 4; i++) {
      int c = tid + (i << 8);
      int d = c >> 3, jc = c & 7;
      uint4 dat = *(const uint4*)(Vb + (size_t)d * 4096 + j0 + jc * 8);
      *(uint4*)((char*)sV + d * 128 + ((jc ^ (d & 7)) << 4)) = dat;
    }
    __syncthreads();

    f32x4 sj[4];
#pragma unroll
    for (int jf = 0; jf < 4; jf++) {
      f32x4 s = {0.f, 0.f, 0.f, 0.f};
      const int j = jf * 16 + lr;
#pragma unroll
      for (int ks = 0; ks < 4; ks++) {
        const int cc = ks * 4 + g;
        h16x8 kb = *(const h16x8*)((char*)sK + j * 256 + ((cc ^ (j & 7)) << 4));
        s = mfma16(qv[ks], kb, s);
      }
      sj[jf] = s;
    }
    const bool maskt = (jt == ntiles - 1);
    float pm[4] = {-1e30f, -1e30f, -1e30f, -1e30f};
#pragma unroll
    for (int jf = 0; jf < 4; jf++)
#pragma unroll
      for (int r = 0; r < 4; r++) {
        float val = sj[jf][r] * sc;
        if (maskt) {
          int jg = j0 + jf * 16 + lr;
          int qg = q0 + w * 16 + g * 4 + r;
          if (jg > 2048 + qg) val = -1e30f;
        }
        sj[jf][r] = val;
        pm[r] = fmaxf(pm[r], val);
      }
#pragma unroll
    for (int r = 0; r < 4; r++)
#pragma unroll
      for (int off = 1; off < 16; off <<= 1)
        pm[r] = fmaxf(pm[r], __shfl_xor(pm[r], off, 16));
    float al[4], rs[4];
#pragma unroll
    for (int r = 0; r < 4; r++) {
      float mn = fmaxf(mrow[r], pm[r]);
      al[r] = __expf(mrow[r] - mn);
      mrow[r] = mn;
      rs[r] = 0.f;
    }
#pragma unroll
    for (int jf = 0; jf < 4; jf++)
#pragma unroll
      for (int r = 0; r < 4; r++) {
        float p = __expf(sj[jf][r] - mrow[r]);
        rs[r] += p;
        int qrow = g * 4 + r;
        int j = jf * 16 + lr;
        int cc = j >> 3;
        *(h16*)((char*)sP + w * 2048 + qrow * 128 + ((cc ^ (qrow & 7)) << 4) +
                (j & 7) * 2) = (h16)p;
      }
#pragma unroll
    for (int r = 0; r < 4; r++) {
#pragma unroll
      for (int off = 1; off < 16; off <<= 1) rs[r] += __shfl_xor(rs[r], off, 16);
      lrow[r] = lrow[r] * al[r] + rs[r];
    }
#pragma unroll
    for (int d = 0; d < 8; ++d)
#pragma unroll
      for (int r = 0; r < 4; r++) oacc[d][r] *= al[r];
#pragma unroll
    for (int ks = 0; ks < 2; ++ks) {
      const int cc = ks * 4 + g;
      h16x8 pa = *(const h16x8*)((char*)sP + w * 2048 + lr * 128 +
                                 ((cc ^ (lr & 7)) << 4));
#pragma unroll
      for (int df = 0; df < 8; ++df) {
        const int d = df * 16 + lr;
        h16x8 vb = *(const h16x8*)((char*)sV + d * 128 + ((cc ^ (d & 7)) << 4));
        oacc[df] = mfma16(pa, vb, oacc[df]);
      }
    }
  }
  h16* Op = O + (size_t)(q0 + w * 16 + g * 4) * 4096 + h * 128 + lr;
#pragma unroll
  for (int df = 0; df < 8; ++df)
#pragma unroll
    for (int r = 0; r < 4; r++) {
      float val = oacc[df][r] / lrow[r];
      Op[(size_t)r * 4096 + df * 16] = (h16)val;
    }
}

extern "C" void kernel_launch(void* const* d_in, const int* in_sizes, int n_in,
                              void* d_out, int out_size, void* d_ws, size_t ws_size,
                              hipStream_t stream) {
  const float* x = (const float*)d_in[0];
  const float* freqs = (const float*)d_in[2];
  const float* oldK = (const float*)d_in[3];
  const float* oldV = (const float*)d_in[4];
  const float* wq = (const float*)d_in[5];
  const float* wk = (const float*)d_in[6];
  const float* wvp = (const float*)d_in[7];
  const float* wo = (const float*)d_in[8];
  const float* w1 = (const float*)d_in[9];
  const float* w2 = (const float*)d_in[10];
  const float* w3 = (const float*)d_in[11];
  const float* anw = (const float*)d_in[12];
  const float* fnw = (const float*)d_in[13];
  float* out = (float*)d_out;
  float* outK = out + 8388608;
  float* outV = out + 12582912;

  char* ws = (char*)d_ws;
  // layout, peak 160 MiB (proven-safe envelope):
  h16* xn = (h16*)(ws + 0);                   // 16.78 MB f16 [2048][4096]
  h16* bufW = (h16*)(ws + 16777216);          // 58.72 MB tiled f16 weights (reused)
  float* hbuf = (float*)(ws + 75497472);      // 33.55 MB f32 [2048][4096]
  //   aliased inside hbuf span until attn done:
  float* kvraw = (float*)(ws + 75497472);     // 16.78 MB f32 [2048][2048]
  h16* kf = (h16*)(ws + 92274688);            //  8.39 MB
  h16* vt = (h16*)(ws + 100663296);           //  8.39 MB
  h16* ub = (h16*)(ws + 109051904);           // 58.72 MB f16 [2048][14336]
  //   aliased inside ub span until FFN:
  h16* qraw = (h16*)(ws + 109051904);         // 16.78 MB
  h16* attnb = (h16*)(ws + 125829120);        // 16.78 MB

  // attention path
  rmsnorm_k<<<2048, 256, 0, stream>>>(x, anw, xn);
  convw_k<<<dim3(32, 64), 256, 0, stream>>>(wq, bufW, 4096, 64);
  gemm_k<1><<<dim3(32, 16), 256, 0, stream>>>(xn, bufW, nullptr, qraw, nullptr,
                                              nullptr, 4096, 4096, 4096, 0);
  convw_k<<<dim3(8, 64), 256, 0, stream>>>(wk, bufW, 1024, 64);
  convw_k<<<dim3(8, 64), 256, 0, stream>>>(wvp, bufW + ((size_t)8 * 64 << 13), 1024, 64);
  gemm_k<0><<<dim3(16, 16), 256, 0, stream>>>(xn, bufW, kvraw, nullptr, nullptr,
                                              nullptr, 4096, 4096, 2048, 0);
  rope_q_k<<<2048, 256, 0, stream>>>(qraw, freqs, qraw);
  cache_build_k<<<dim3(64, 8), 256, 0, stream>>>(oldK, oldV, kvraw, freqs, outK,
                                                 outV, kf, vt);
  attn_k<<<dim3(32, 32), 256, 0, stream>>>(qraw, kf, vt, attnb);
  convw_k<<<dim3(32, 64), 256, 0, stream>>>(wo, bufW, 4096, 64);
  gemm_k<2><<<dim3(32, 16), 256, 0, stream>>>(attnb, bufW, hbuf, nullptr, x,
                                              nullptr, 4096, 4096, 4096, 0);
  // FFN path
  rmsnorm_k<<<2048, 256, 0, stream>>>(hbuf, fnw, xn);
  // w1 in two N-halves -> ub
  convw_k<<<dim3(56, 64), 256, 0, stream>>>(w1, bufW, 14336, 64);
  gemm_k<1><<<dim3(56, 16), 256, 0, stream>>>(xn, bufW, nullptr, ub, nullptr,
                                              nullptr, 4096, 4096, 14336, 0);
  convw_k<<<dim3(56, 64), 256, 0, stream>>>(w1 + 7168, bufW, 14336, 64);
  gemm_k<1><<<dim3(56, 16), 256, 0, stream>>>(xn, bufW, nullptr, ub, nullptr,
                                              nullptr, 4096, 4096, 14336, 7168);
  // w3 in two N-halves, fused ub = silu(ub) * (xn@w3)
  convw_k<<<dim3(56, 64), 256, 0, stream>>>(w3, bufW, 14336, 64);
  gemm_k<3><<<dim3(56, 16), 256, 0, stream>>>(xn, bufW, nullptr, ub, nullptr, ub,
                                              4096, 4096, 14336, 0);
  convw_k<<<dim3(56, 64), 256, 0, stream>>>(w3 + 7168, bufW, 14336, 64);
  gemm_k<3><<<dim3(56, 16), 256, 0, stream>>>(xn, bufW, nullptr, ub, nullptr, ub,
                                              4096, 4096, 14336, 7168);
  // w2 in two K-halves: out = hbuf + ub@w2
  convw_k<<<dim3(32, 112), 256, 0, stream>>>(w2, bufW, 4096, 112);
  gemm_k<2><<<dim3(32, 16), 256, 0, stream>>>(ub, bufW, out, nullptr, hbuf,
                                              nullptr, 7168, 14336, 4096, 0);
  convw_k<<<dim3(32, 112), 256, 0, stream>>>(w2 + (size_t)7168 * 4096, bufW, 4096, 112);
  gemm_k<4><<<dim3(32, 16), 256, 0, stream>>>(ub + 7168, bufW, out, nullptr,
                                              nullptr, nullptr, 7168, 14336, 4096, 0);
}

// Round 5
// 1833.205 us; speedup vs baseline: 3.0545x; 1.0055x over previous
//
#include <hip/hip_runtime.h>

typedef _Float16 h16;
typedef _Float16 h16x4 __attribute__((ext_vector_type(4)));
typedef _Float16 h16x8 __attribute__((ext_vector_type(8)));
typedef float f32x4 __attribute__((ext_vector_type(4)));
typedef float f32x16 __attribute__((ext_vector_type(16)));
typedef unsigned short u16;

__device__ __forceinline__ f32x4 mfma16(h16x8 a, h16x8 b, f32x4 c) {
  return __builtin_amdgcn_mfma_f32_16x16x32_f16(a, b, c, 0, 0, 0);
}
__device__ __forceinline__ f32x16 mfma32(h16x8 a, h16x8 b, f32x16 c) {
  return __builtin_amdgcn_mfma_f32_32x32x16_f16(a, b, c, 0, 0, 0);
}

typedef const __attribute__((address_space(1))) void* gas_p;
typedef __attribute__((address_space(3))) void* las_p;
__device__ __forceinline__ void ldscp16(const void* g, void* l) {
  __builtin_amdgcn_global_load_lds((gas_p)g, (las_p)l, 16, 0, 0);
}

// ---------------- RMSNorm: f32 [2048][4096] -> f16 ----------------
__global__ __launch_bounds__(256) void rmsnorm_k(
    const float* __restrict__ x, const float* __restrict__ w, h16* __restrict__ out) {
  const int row = blockIdx.x, t = threadIdx.x;
  const float* xr = x + (size_t)row * 4096;
  float4 v[4];
  float ss = 0.f;
#pragma unroll
  for (int j = 0; j < 4; j++) {
    v[j] = *(const float4*)(xr + 4 * t + 1024 * j);
    ss += v[j].x * v[j].x + v[j].y * v[j].y + v[j].z * v[j].z + v[j].w * v[j].w;
  }
#pragma unroll
  for (int off = 1; off < 64; off <<= 1) ss += __shfl_xor(ss, off, 64);
  __shared__ float red[4];
  if ((t & 63) == 0) red[t >> 6] = ss;
  __syncthreads();
  float scale = rsqrtf((red[0] + red[1] + red[2] + red[3]) * (1.f / 4096.f) + 1e-6f);
  h16* orow = out + (size_t)row * 4096;
#pragma unroll
  for (int j = 0; j < 4; j++) {
    float4 wv = *(const float4*)(w + 4 * t + 1024 * j);
    h16x4 o;
    o[0] = (h16)(v[j].x * scale * wv.x);
    o[1] = (h16)(v[j].y * scale * wv.y);
    o[2] = (h16)(v[j].z * scale * wv.z);
    o[3] = (h16)(v[j].w * scale * wv.w);
    *(h16x4*)(orow + 4 * t + 1024 * j) = o;
  }
}

// ------- weight convert: f32 -> f16 tiled+swizzled LDS images -------
__global__ __launch_bounds__(256) void convw_k(
    const float* __restrict__ W, h16* __restrict__ out, int rowN, int ktiles) {
  __shared__ u16 timg[8192];
  const int t = threadIdx.x, b = blockIdx.x, kt = blockIdx.y;
  const float* src = W + (size_t)(kt * 64) * rowN + b * 128;
#pragma unroll
  for (int i = 0; i < 8; i++) {
    int c = t + (i << 8);
    int krow = c >> 5, nc = (c & 31) << 2;
    float4 v = *(const float4*)(src + (size_t)krow * rowN + nc);
    int kc = krow >> 3, e = krow & 7;
    float vals[4] = {v.x, v.y, v.z, v.w};
#pragma unroll
    for (int j = 0; j < 4; j++) {
      int m = nc + j;
      h16 hv = (h16)vals[j];
      timg[(m << 6) + ((kc ^ (m & 7)) << 3) + e] = __builtin_bit_cast(u16, hv);
    }
  }
  __syncthreads();
  uint4* dst = (uint4*)(out + ((size_t)(b * ktiles + kt) << 13));
  const uint4* s4 = (const uint4*)timg;
#pragma unroll
  for (int i = 0; i < 4; i++) dst[t + (i << 8)] = s4[t + (i << 8)];
}

// ---------------- GEMM, 2-phase double-buffered ----------------
// EPI: 0 f32; 1 f16; 2 f32=resid+acc; 3 f16=silu(uin)*acc; 4 f32+=acc;
//      5 split: col<4096 -> f16 qraw, else f32 kvraw (col-4096, ld 2048)
template <int EPI>
__global__ __launch_bounds__(256, 2) void gemm_k(
    const h16* __restrict__ A, const h16* __restrict__ Wt,
    float* outF, h16* outH, const float* resid, const h16* uin,
    int K, int lda, int ldo, int no0) {
  __shared__ u16 sA[2][8192];
  __shared__ u16 sB[2][8192];
  const int tid = threadIdx.x, lane = tid & 63;
  const int wv = tid >> 6, wr = wv >> 1, wc = wv & 1;
  const int g = lane >> 4, lr = lane & 15;
  const int m0 = blockIdx.y << 7, n0 = blockIdx.x << 7;
  const int r8 = lane >> 3, ch = lane & 7;
  const int ktiles = K >> 6;

  f32x4 acc[4][4];
#pragma unroll
  for (int i = 0; i < 4; i++)
#pragma unroll
    for (int j = 0; j < 4; j++) acc[i][j] = {0.f, 0.f, 0.f, 0.f};

  const h16* gA0 = A + (size_t)(m0 + wv * 8 + r8) * lda + ((ch ^ r8) << 3);
  const h16* gB0 = Wt + ((size_t)blockIdx.x * ktiles << 13) + (wv << 9) + (lane << 3);

  auto stage = [&](int kt, int buf) {
    char* lA = (char*)sA[buf] + (wv << 10);
    char* lB = (char*)sB[buf] + (wv << 10);
    const h16* a = gA0 + kt * 64;
    const h16* b = gB0 + (size_t)kt * 8192;
#pragma unroll
    for (int i = 0; i < 4; i++) {
      ldscp16(a + (size_t)i * 32 * lda, lA + i * 4096);
      ldscp16(b + i * 2048, lB + i * 4096);
    }
  };

  stage(0, 0);
  __syncthreads();
  int cur = 0;
  for (int kt = 0; kt < ktiles; ++kt) {
    if (kt + 1 < ktiles) stage(kt + 1, cur ^ 1);
#pragma unroll
    for (int ks = 0; ks < 2; ++ks) {
      h16x8 av[4], bv[4];
#pragma unroll
      for (int f = 0; f < 4; f++) {
        int row = (wr << 6) + (f << 4) + lr;
        int cc = (ks << 2) + g;
        av[f] = *(const h16x8*)((char*)sA[cur] + row * 128 + ((cc ^ (row & 7)) << 4));
        int col = (wc << 6) + (f << 4) + lr;
        bv[f] = *(const h16x8*)((char*)sB[cur] + col * 128 + ((cc ^ (col & 7)) << 4));
      }
#pragma unroll
      for (int fi = 0; fi < 4; fi++)
#pragma unroll
        for (int fj = 0; fj < 4; fj++)
          acc[fi][fj] = mfma16(av[fi], bv[fj], acc[fi][fj]);
    }
    __syncthreads();
    cur ^= 1;
  }
  // epilogue; C/D: col=lane&15, row=(lane>>4)*4+r
#pragma unroll
  for (int fi = 0; fi < 4; fi++) {
    const int row = m0 + (wr << 6) + (fi << 4) + (g << 2);
#pragma unroll
    for (int fj = 0; fj < 4; fj++) {
      const int col = no0 + n0 + (wc << 6) + (fj << 4) + lr;
#pragma unroll
      for (int r = 0; r < 4; r++) {
        float vl = acc[fi][fj][r];
        if constexpr (EPI == 5) {
          if (col < 4096) outH[(size_t)(row + r) * 4096 + col] = (h16)vl;
          else outF[(size_t)(row + r) * 2048 + (col - 4096)] = vl;
        } else {
          size_t idx = (size_t)(row + r) * ldo + col;
          if constexpr (EPI == 0) outF[idx] = vl;
          else if constexpr (EPI == 1) outH[idx] = (h16)vl;
          else if constexpr (EPI == 2) outF[idx] = resid[idx] + vl;
          else if constexpr (EPI == 3) {
            float u = (float)uin[idx];
            outH[idx] = (h16)((u / (1.f + __expf(-u))) * vl);
          } else outF[idx] = outF[idx] + vl;
        }
      }
    }
  }
}

// ---------------- RoPE on Q (f16, in-place safe) ----------------
__global__ __launch_bounds__(256) void rope_q_k(
    const h16* __restrict__ qin, const float* __restrict__ freqs, h16* qout) {
  const int row = blockIdx.x, t = threadIdx.x;
#pragma unroll
  for (int it = 0; it < 8; ++it) {
    int pid = t + 256 * it;
    int head = pid >> 6, pp = pid & 63;
    size_t idx = (size_t)row * 4096 + head * 128 + 2 * pp;
    float x0 = (float)qin[idx], x1 = (float)qin[idx + 1];
    float cs = freqs[row * 128 + 2 * pp], sn = freqs[row * 128 + 2 * pp + 1];
    qout[idx] = (h16)(x0 * cs - x1 * sn);
    qout[idx + 1] = (h16)(x0 * sn + x1 * cs);
  }
}

// ------- build new cache: f32 outs + f16 K [kvh][r][d] + f16 V^T [kvh][d][r] -------
__global__ __launch_bounds__(256) void cache_build_k(
    const float* __restrict__ oldK, const float* __restrict__ oldV,
    const float* __restrict__ kvraw, const float* __restrict__ freqs,
    float* __restrict__ outK, float* __restrict__ outV,
    h16* __restrict__ Kf, h16* __restrict__ Vt) {
  const int rt = blockIdx.x, kvh = blockIdx.y;
  const int r0 = rt * 64, tid = threadIdx.x;
  __shared__ u16 vtile[64][128];
#pragma unroll
  for (int it = 0; it < 16; ++it) {
    int s = tid + 256 * it;
    int rr = s >> 6, pp = s & 63;
    int r = r0 + rr;
    float k0, k1, v0, v1;
    if (r < 2048) {
      const float* kp = oldK + (size_t)(r + 2048) * 1024 + kvh * 128 + 2 * pp;
      k0 = kp[0]; k1 = kp[1];
      const float* vp = oldV + (size_t)(r + 2048) * 1024 + kvh * 128 + 2 * pp;
      v0 = vp[0]; v1 = vp[1];
    } else {
      int tpos = r - 2048;
      const float* kp = kvraw + (size_t)tpos * 2048 + kvh * 128 + 2 * pp;
      float x0 = kp[0], x1 = kp[1];
      float cs = freqs[tpos * 128 + 2 * pp], sn = freqs[tpos * 128 + 2 * pp + 1];
      k0 = x0 * cs - x1 * sn;
      k1 = x0 * sn + x1 * cs;
      const float* vp = kvraw + (size_t)tpos * 2048 + 1024 + kvh * 128 + 2 * pp;
      v0 = vp[0]; v1 = vp[1];
    }
    size_t oidx = (size_t)r * 1024 + kvh * 128 + 2 * pp;
    outK[oidx] = k0; outK[oidx + 1] = k1;
    outV[oidx] = v0; outV[oidx + 1] = v1;
    size_t kfi = (size_t)kvh * 524288 + (size_t)r * 128 + 2 * pp;
    Kf[kfi] = (h16)k0; Kf[kfi + 1] = (h16)k1;
    h16 h0 = (h16)v0, h1 = (h16)v1;
    vtile[rr][2 * pp] = __builtin_bit_cast(u16, h0);
    vtile[rr][2 * pp + 1] = __builtin_bit_cast(u16, h1);
  }
  __syncthreads();
#pragma unroll
  for (int it = 0; it < 4; ++it) {
    int c = tid + 256 * it;
    int d = c >> 3, rg = c & 7;
    u16 tmp[8];
#pragma unroll
    for (int u = 0; u < 8; u++) tmp[u] = vtile[rg * 8 + u][d];
    *(uint4*)((u16*)Vt + (size_t)kvh * 524288 + (size_t)d * 4096 + r0 + rg * 8) =
        *(uint4*)tmp;
  }
}

// ---------------- flash attention v2: 32x32 MFMA, swapped QK^T ----------------
// block: 4 waves x 32 q (QBLK=128); S^T per lane: 1 q, 32 j; O^T accum.
__global__ __launch_bounds__(256) void attn_k(
    const h16* __restrict__ Q, const h16* __restrict__ Kf,
    const h16* __restrict__ Vt, h16* __restrict__ O) {
  __shared__ u16 sK[2][8192];  // [j 64][d 128], 16B-chunk ^ (j&15)
  __shared__ u16 sV[2][8192];  // [d 128][j 64], 16B-chunk ^ (d&7)
  __shared__ u16 sP[4][2048];  // per-wave [q 32][j 64], chunk ^ (q&7)
  const int qt = 15 - blockIdx.x, h = blockIdx.y;
  const int q0 = qt << 7, kvh = h >> 2;
  const int tid = threadIdx.x, w = tid >> 6, lane = tid & 63;
  const int lq = lane & 31, lh = lane >> 5;
  const h16* Kb = Kf + (size_t)kvh * 524288;
  const h16* Vb = Vt + (size_t)kvh * 524288;

  h16x8 qv[8];
  {
    const h16* qp = Q + (size_t)(q0 + w * 32 + lq) * 4096 + h * 128 + (lh << 3);
#pragma unroll
    for (int c = 0; c < 8; c++) qv[c] = *(const h16x8*)(qp + c * 16);
  }
  f32x16 oa[4];
#pragma unroll
  for (int d = 0; d < 4; d++)
#pragma unroll
    for (int v = 0; v < 16; v++) oa[d][v] = 0.f;
  float m2 = -3e38f, l2 = 0.f;
  const int ntiles = 34 + 2 * qt;
  const float sc = 0.08838834764831845f;
  const int qg = q0 + w * 32 + lq;

  auto stage = [&](int buf, int j0s) {
    char* dK = (char*)sK[buf];
    char* dV = (char*)sV[buf];
#pragma unroll
    for (int i = 0; i < 4; i++) {
      int c = tid + (i << 8);
      int jl = c >> 4, kch = c & 15;
      ldscp16(Kb + (size_t)(j0s + jl) * 128 + ((kch ^ (jl & 15)) << 3), dK + c * 16);
      int dl = c >> 3, jch = c & 7;
      ldscp16(Vb + (size_t)dl * 4096 + j0s + ((jch ^ (dl & 7)) << 3), dV + c * 16);
    }
  };

  stage(0, 0);
  __syncthreads();
  int cur = 0;
  for (int jt = 0; jt < ntiles; ++jt) {
    if (jt + 1 < ntiles) stage(cur ^ 1, (jt + 1) << 6);
    const char* bK = (const char*)sK[cur];
    const char* bV = (const char*)sV[cur];
    // QK^T swapped: S^T = K x Q
    f32x16 st[2];
#pragma unroll
    for (int jb = 0; jb < 2; jb++) {
      f32x16 s;
#pragma unroll
      for (int v = 0; v < 16; v++) s[v] = 0.f;
      const int jr = jb * 32 + lq;
#pragma unroll
      for (int kc = 0; kc < 8; kc++) {
        h16x8 ak =
            *(const h16x8*)(bK + jr * 256 + ((((kc << 1) + lh) ^ (jr & 15)) << 4));
        s = mfma32(ak, qv[kc], s);
      }
      st[jb] = s;
    }
    // scale + mask + row max
    const int j0 = jt << 6;
    const bool domask = (jt >= ntiles - 2);
    float pm = -3e38f;
#pragma unroll
    for (int jb = 0; jb < 2; jb++)
#pragma unroll
      for (int v = 0; v < 16; v++) {
        float val = st[jb][v] * sc;
        if (domask) {
          int j = j0 + jb * 32 + (v & 3) + (((v >> 2) & 3) << 3) + (lh << 2);
          if (j > 2048 + qg) val = -1e30f;
        }
        st[jb][v] = val;
        pm = fmaxf(pm, val);
      }
    pm = fmaxf(pm, __shfl_xor(pm, 32, 64));
    if (__any(pm - m2 > 8.f)) {  // defer-max (T13)
      float mn = fmaxf(m2, pm);
      float al = __expf(m2 - mn);
      m2 = mn;
      l2 *= al;
#pragma unroll
      for (int d = 0; d < 4; d++) oa[d] *= al;
    }
    float rs = 0.f;
#pragma unroll
    for (int jb = 0; jb < 2; jb++)
#pragma unroll
      for (int v = 0; v < 16; v++) {
        float p = __expf(st[jb][v] - m2);
        st[jb][v] = p;
        rs += p;
      }
    rs += __shfl_xor(rs, 32, 64);
    l2 += rs;
    // P -> per-wave LDS (packed 8B, swizzled)
    char* pw = (char*)sP[w];
#pragma unroll
    for (int jb = 0; jb < 2; jb++)
#pragma unroll
      for (int b = 0; b < 4; b++) {
        h16x4 ph;
#pragma unroll
        for (int i = 0; i < 4; i++) ph[i] = (h16)st[jb][(b << 2) + i];
        *(h16x4*)(pw + lq * 128 + ((((jb << 2) + b) ^ (lq & 7)) << 4) + (lh << 3)) =
            ph;
      }
    // PV: O^T = V^T x P^T
    h16x8 pb[4];
#pragma unroll
    for (int kc = 0; kc < 4; kc++)
      pb[kc] = *(const h16x8*)(pw + lq * 128 + ((((kc << 1) + lh) ^ (lq & 7)) << 4));
#pragma unroll
    for (int d = 0; d < 4; d++) {
      const int dr = (d << 5) + lq;
#pragma unroll
      for (int kc = 0; kc < 4; kc++) {
        h16x8 av =
            *(const h16x8*)(bV + dr * 128 + ((((kc << 1) + lh) ^ (dr & 7)) << 4));
        oa[d] = mfma32(av, pb[kc], oa[d]);
      }
    }
    __syncthreads();
    cur ^= 1;
  }
  float rl = 1.f / l2;
  h16* Op = O + (size_t)qg * 4096 + h * 128;
#pragma unroll
  for (int d = 0; d < 4; d++)
#pragma unroll
    for (int b = 0; b < 4; b++) {
      h16x4 ov;
#pragma unroll
      for (int i = 0; i < 4; i++) ov[i] = (h16)(oa[d][(b << 2) + i] * rl);
      *(h16x4*)(Op + (d << 5) + (b << 3) + (lh << 2)) = ov;
    }
}

extern "C" void kernel_launch(void* const* d_in, const int* in_sizes, int n_in,
                              void* d_out, int out_size, void* d_ws, size_t ws_size,
                              hipStream_t stream) {
  const float* x = (const float*)d_in[0];
  const float* freqs = (const float*)d_in[2];
  const float* oldK = (const float*)d_in[3];
  const float* oldV = (const float*)d_in[4];
  const float* wq = (const float*)d_in[5];
  const float* wk = (const float*)d_in[6];
  const float* wvp = (const float*)d_in[7];
  const float* wo = (const float*)d_in[8];
  const float* w1 = (const float*)d_in[9];
  const float* w2 = (const float*)d_in[10];
  const float* w3 = (const float*)d_in[11];
  const float* anw = (const float*)d_in[12];
  const float* fnw = (const float*)d_in[13];
  float* out = (float*)d_out;
  float* outK = out + 8388608;
  float* outV = out + 12582912;

  char* ws = (char*)d_ws;
  // layout, peak 160 MiB (proven-safe)
  h16* xn = (h16*)(ws + 0);                // 16.78 MB f16 [2048][4096]
  h16* bufW = (h16*)(ws + 16777216);       // 58.72 MB tiled f16 weights (reused)
  float* hbuf = (float*)(ws + 75497472);   // 33.55 MB f32 [2048][4096]
  float* kvraw = (float*)(ws + 75497472);  // 16.78 MB f32 [2048][2048] (aliased)
  h16* kf = (h16*)(ws + 92274688);         //  8.39 MB
  h16* vt = (h16*)(ws + 100663296);        //  8.39 MB
  h16* ub = (h16*)(ws + 109051904);        // 58.72 MB f16 [2048][14336]
  h16* qraw = (h16*)(ws + 109051904);      // 16.78 MB (aliased in ub span)
  h16* attnb = (h16*)(ws + 125829120);     // 16.78 MB (aliased in ub span)

  // attention path
  rmsnorm_k<<<2048, 256, 0, stream>>>(x, anw, xn);
  convw_k<<<dim3(32, 64), 256, 0, stream>>>(wq, bufW, 4096, 64);
  convw_k<<<dim3(8, 64), 256, 0, stream>>>(wk, bufW + ((size_t)32 * 64 << 13), 1024, 64);
  convw_k<<<dim3(8, 64), 256, 0, stream>>>(wvp, bufW + ((size_t)40 * 64 << 13), 1024, 64);
  gemm_k<5><<<dim3(48, 16), 256, 0, stream>>>(xn, bufW, kvraw, qraw, nullptr,
                                              nullptr, 4096, 4096, 0, 0);
  rope_q_k<<<2048, 256, 0, stream>>>(qraw, freqs, qraw);
  cache_build_k<<<dim3(64, 8), 256, 0, stream>>>(oldK, oldV, kvraw, freqs, outK,
                                                 outV, kf, vt);
  attn_k<<<dim3(16, 32), 256, 0, stream>>>(qraw, kf, vt, attnb);
  convw_k<<<dim3(32, 64), 256, 0, stream>>>(wo, bufW, 4096, 64);
  gemm_k<2><<<dim3(32, 16), 256, 0, stream>>>(attnb, bufW, hbuf, nullptr, x,
                                              nullptr, 4096, 4096, 4096, 0);
  // FFN path
  rmsnorm_k<<<2048, 256, 0, stream>>>(hbuf, fnw, xn);
  convw_k<<<dim3(56, 64), 256, 0, stream>>>(w1, bufW, 14336, 64);
  gemm_k<1><<<dim3(56, 16), 256, 0, stream>>>(xn, bufW, nullptr, ub, nullptr,
                                              nullptr, 4096, 4096, 14336, 0);
  convw_k<<<dim3(56, 64), 256, 0, stream>>>(w1 + 7168, bufW, 14336, 64);
  gemm_k<1><<<dim3(56, 16), 256, 0, stream>>>(xn, bufW, nullptr, ub, nullptr,
                                              nullptr, 4096, 4096, 14336, 7168);
  convw_k<<<dim3(56, 64), 256, 0, stream>>>(w3, bufW, 14336, 64);
  gemm_k<3><<<dim3(56, 16), 256, 0, stream>>>(xn, bufW, nullptr, ub, nullptr, ub,
                                              4096, 4096, 14336, 0);
  convw_k<<<dim3(56, 64), 256, 0, stream>>>(w3 + 7168, bufW, 14336, 64);
  gemm_k<3><<<dim3(56, 16), 256, 0, stream>>>(xn, bufW, nullptr, ub, nullptr, ub,
                                              4096, 4096, 14336, 7168);
  convw_k<<<dim3(32, 112), 256, 0, stream>>>(w2, bufW, 4096, 112);
  gemm_k<2><<<dim3(32, 16), 256, 0, stream>>>(ub, bufW, out, nullptr, hbuf,
                                              nullptr, 7168, 14336, 4096, 0);
  convw_k<<<dim3(32, 112), 256, 0, stream>>>(w2 + (size_t)7168 * 4096, bufW, 4096, 112);
  gemm_k<4><<<dim3(32, 16), 256, 0, stream>>>(ub + 7168, bufW, out, nullptr,
                                              nullptr, nullptr, 7168, 14336, 4096, 0);
}

// Round 6
// 1710.430 us; speedup vs baseline: 3.2737x; 1.0718x over previous
//
#include <hip/hip_runtime.h>

typedef _Float16 h16;
typedef _Float16 h16x4 __attribute__((ext_vector_type(4)));
typedef _Float16 h16x8 __attribute__((ext_vector_type(8)));
typedef float f32x4 __attribute__((ext_vector_type(4)));
typedef float f32x16 __attribute__((ext_vector_type(16)));
typedef unsigned short u16;
typedef unsigned long long u64;

__device__ __forceinline__ f32x4 mfma16(h16x8 a, h16x8 b, f32x4 c) {
  return __builtin_amdgcn_mfma_f32_16x16x32_f16(a, b, c, 0, 0, 0);
}
__device__ __forceinline__ f32x16 mfma32(h16x8 a, h16x8 b, f32x16 c) {
  return __builtin_amdgcn_mfma_f32_32x32x16_f16(a, b, c, 0, 0, 0);
}

typedef const __attribute__((address_space(1))) void* gas_p;
typedef __attribute__((address_space(3))) void* las_p;
__device__ __forceinline__ void ldscp16(const void* g, void* l) {
  __builtin_amdgcn_global_load_lds((gas_p)g, (las_p)l, 16, 0, 0);
}
#define VMCNT(n) asm volatile("s_waitcnt vmcnt(" #n ")" ::: "memory")
#define SBAR() asm volatile("s_barrier" ::: "memory")

// ---------------- RMSNorm: f32 [2048][4096] -> f16 ----------------
__global__ __launch_bounds__(256) void rmsnorm_k(
    const float* __restrict__ x, const float* __restrict__ w, h16* __restrict__ out) {
  const int row = blockIdx.x, t = threadIdx.x;
  const float* xr = x + (size_t)row * 4096;
  float4 v[4];
  float ss = 0.f;
#pragma unroll
  for (int j = 0; j < 4; j++) {
    v[j] = *(const float4*)(xr + 4 * t + 1024 * j);
    ss += v[j].x * v[j].x + v[j].y * v[j].y + v[j].z * v[j].z + v[j].w * v[j].w;
  }
#pragma unroll
  for (int off = 1; off < 64; off <<= 1) ss += __shfl_xor(ss, off, 64);
  __shared__ float red[4];
  if ((t & 63) == 0) red[t >> 6] = ss;
  __syncthreads();
  float scale = rsqrtf((red[0] + red[1] + red[2] + red[3]) * (1.f / 4096.f) + 1e-6f);
  h16* orow = out + (size_t)row * 4096;
#pragma unroll
  for (int j = 0; j < 4; j++) {
    float4 wv = *(const float4*)(w + 4 * t + 1024 * j);
    h16x4 o;
    o[0] = (h16)(v[j].x * scale * wv.x);
    o[1] = (h16)(v[j].y * scale * wv.y);
    o[2] = (h16)(v[j].z * scale * wv.z);
    o[3] = (h16)(v[j].w * scale * wv.w);
    *(h16x4*)(orow + 4 * t + 1024 * j) = o;
  }
}

// ------- weight convert: f32 -> f16 tiled+swizzled LDS images -------
__global__ __launch_bounds__(256) void convw_k(
    const float* __restrict__ W, h16* __restrict__ out, int rowN, int ktiles) {
  __shared__ u16 timg[8192];
  const int t = threadIdx.x, b = blockIdx.x, kt = blockIdx.y;
  const float* src = W + (size_t)(kt * 64) * rowN + b * 128;
#pragma unroll
  for (int i = 0; i < 8; i++) {
    int c = t + (i << 8);
    int krow = c >> 5, nc = (c & 31) << 2;
    float4 v = *(const float4*)(src + (size_t)krow * rowN + nc);
    int kc = krow >> 3, e = krow & 7;
    float vals[4] = {v.x, v.y, v.z, v.w};
#pragma unroll
    for (int j = 0; j < 4; j++) {
      int m = nc + j;
      h16 hv = (h16)vals[j];
      timg[(m << 6) + ((kc ^ (m & 7)) << 3) + e] = __builtin_bit_cast(u16, hv);
    }
  }
  __syncthreads();
  uint4* dst = (uint4*)(out + ((size_t)(b * ktiles + kt) << 13));
  const uint4* s4 = (const uint4*)timg;
#pragma unroll
  for (int i = 0; i < 4; i++) dst[t + (i << 8)] = s4[t + (i << 8)];
}

// ---------------- GEMM: 512 thr, BM=128 BN=256 BK=64, 3-buf counted pipeline --------
// EPI: 1 f16; 2 f32=resid+acc; 3 f16=silu(uin)*acc; 4 f32+=acc;
//      5 split: col<4096 -> f16 qraw, else f32 kvraw (col-4096, ld 2048)
template <int EPI>
__global__ __launch_bounds__(512, 2) void gemm_k(
    const h16* __restrict__ A, const h16* __restrict__ Wt,
    float* outF, h16* outH, const float* resid, const h16* uin,
    int K, int lda, int ldo, int no0) {
  __shared__ u16 lds[3][24576];  // per buf: A[128][64] @0 (16KB), B[256][64] @16KB (32KB)
  const int tid = threadIdx.x, lane = tid & 63;
  const int wv = tid >> 6, wr = wv >> 2, wc = wv & 3;
  const int g = lane >> 4, lr = lane & 15;
  const int m0 = blockIdx.y << 7, n0 = blockIdx.x << 8;
  const int ktiles = K >> 6;

  f32x4 acc[4][4];
#pragma unroll
  for (int i = 0; i < 4; i++)
#pragma unroll
    for (int j = 0; j < 4; j++) acc[i][j] = {0.f, 0.f, 0.f, 0.f};

  // staging sources
  const int rA = tid >> 3;
  const int kcA = (tid & 7) ^ (rA & 7);
  const h16* gA = A + (size_t)(m0 + rA) * lda + (kcA << 3);
  const h16* gA2 = gA + (size_t)64 * lda;
  const h16* gB0 = Wt + (((size_t)(2 * blockIdx.x) * ktiles) << 13) + tid * 8;
  const h16* gB1 = Wt + (((size_t)(2 * blockIdx.x + 1) * ktiles) << 13) + tid * 8;

  auto issueA = [&](int t) {  // A unit + B unit0 (4 loads)
    char* base = (char*)lds[t % 3];
    ldscp16(gA + t * 64, base + tid * 16);
    ldscp16(gA2 + t * 64, base + tid * 16 + 8192);
    ldscp16(gB0 + ((size_t)t << 13), base + 16384 + tid * 16);
    ldscp16(gB0 + ((size_t)t << 13) + 4096, base + 16384 + tid * 16 + 8192);
  };
  auto issueB = [&](int t) {  // B unit1 (2 loads)
    char* base = (char*)lds[t % 3];
    ldscp16(gB1 + ((size_t)t << 13), base + 32768 + tid * 16);
    ldscp16(gB1 + ((size_t)t << 13) + 4096, base + 32768 + tid * 16 + 8192);
  };

  issueA(0); issueB(0); issueA(1); issueB(1);
  VMCNT(6);
  SBAR();

  for (int t = 0; t < ktiles; ++t) {
    const char* bp = (const char*)lds[t % 3];
    const bool more = (t + 2 < ktiles);
#pragma unroll
    for (int ks = 0; ks < 2; ++ks) {
      h16x8 av[4], bv[4];
      const int cc = (ks << 2) + g;
#pragma unroll
      for (int f = 0; f < 4; f++) {
        int row = (wr << 6) + (f << 4) + lr;
        av[f] = *(const h16x8*)(bp + row * 128 + ((cc ^ (row & 7)) << 4));
        int nr = (wc << 6) + (f << 4) + lr;
        bv[f] = *(const h16x8*)(bp + 16384 + nr * 128 + ((cc ^ (nr & 7)) << 4));
      }
      if (more) {
        if (ks == 0) issueA(t + 2);
        else issueB(t + 2);
      }
      __builtin_amdgcn_s_setprio(1);
#pragma unroll
      for (int fi = 0; fi < 4; fi++)
#pragma unroll
        for (int fj = 0; fj < 4; fj++)
          acc[fi][fj] = mfma16(av[fi], bv[fj], acc[fi][fj]);
      __builtin_amdgcn_s_setprio(0);
    }
    if (t + 1 < ktiles) {
      if (more) VMCNT(6);
      else VMCNT(0);
      SBAR();
    }
  }
  // epilogue; C/D: col=lane&15, row=(lane>>4)*4+r
#pragma unroll
  for (int fi = 0; fi < 4; fi++) {
    const int row = m0 + (wr << 6) + (fi << 4) + (g << 2);
#pragma unroll
    for (int fj = 0; fj < 4; fj++) {
      const int col = no0 + n0 + (wc << 6) + (fj << 4) + lr;
#pragma unroll
      for (int r = 0; r < 4; r++) {
        float vl = acc[fi][fj][r];
        if constexpr (EPI == 5) {
          if (col < 4096) outH[(size_t)(row + r) * 4096 + col] = (h16)vl;
          else outF[(size_t)(row + r) * 2048 + (col - 4096)] = vl;
        } else {
          size_t idx = (size_t)(row + r) * ldo + col;
          if constexpr (EPI == 1) outH[idx] = (h16)vl;
          else if constexpr (EPI == 2) outF[idx] = resid[idx] + vl;
          else if constexpr (EPI == 3) {
            float u = (float)uin[idx];
            outH[idx] = (h16)((u / (1.f + __expf(-u))) * vl);
          } else outF[idx] = outF[idx] + vl;
        }
      }
    }
  }
}

// ---------------- RoPE on Q (f16, in-place safe) ----------------
__global__ __launch_bounds__(256) void rope_q_k(
    const h16* __restrict__ qin, const float* __restrict__ freqs, h16* qout) {
  const int row = blockIdx.x, t = threadIdx.x;
#pragma unroll
  for (int it = 0; it < 8; ++it) {
    int pid = t + 256 * it;
    int head = pid >> 6, pp = pid & 63;
    size_t idx = (size_t)row * 4096 + head * 128 + 2 * pp;
    float x0 = (float)qin[idx], x1 = (float)qin[idx + 1];
    float cs = freqs[row * 128 + 2 * pp], sn = freqs[row * 128 + 2 * pp + 1];
    qout[idx] = (h16)(x0 * cs - x1 * sn);
    qout[idx + 1] = (h16)(x0 * sn + x1 * cs);
  }
}

// ------- build new cache: f32 outs + f16 K [kvh][r][d] + f16 V^T [kvh][d][r] -------
__global__ __launch_bounds__(256) void cache_build_k(
    const float* __restrict__ oldK, const float* __restrict__ oldV,
    const float* __restrict__ kvraw, const float* __restrict__ freqs,
    float* __restrict__ outK, float* __restrict__ outV,
    h16* __restrict__ Kf, h16* __restrict__ Vt) {
  const int rt = blockIdx.x, kvh = blockIdx.y;
  const int r0 = rt * 64, tid = threadIdx.x;
  __shared__ u16 vtile[64][128];
#pragma unroll
  for (int it = 0; it < 16; ++it) {
    int s = tid + 256 * it;
    int rr = s >> 6, pp = s & 63;
    int r = r0 + rr;
    float k0, k1, v0, v1;
    if (r < 2048) {
      const float* kp = oldK + (size_t)(r + 2048) * 1024 + kvh * 128 + 2 * pp;
      k0 = kp[0]; k1 = kp[1];
      const float* vp = oldV + (size_t)(r + 2048) * 1024 + kvh * 128 + 2 * pp;
      v0 = vp[0]; v1 = vp[1];
    } else {
      int tpos = r - 2048;
      const float* kp = kvraw + (size_t)tpos * 2048 + kvh * 128 + 2 * pp;
      float x0 = kp[0], x1 = kp[1];
      float cs = freqs[tpos * 128 + 2 * pp], sn = freqs[tpos * 128 + 2 * pp + 1];
      k0 = x0 * cs - x1 * sn;
      k1 = x0 * sn + x1 * cs;
      const float* vp = kvraw + (size_t)tpos * 2048 + 1024 + kvh * 128 + 2 * pp;
      v0 = vp[0]; v1 = vp[1];
    }
    size_t oidx = (size_t)r * 1024 + kvh * 128 + 2 * pp;
    outK[oidx] = k0; outK[oidx + 1] = k1;
    outV[oidx] = v0; outV[oidx + 1] = v1;
    size_t kfi = (size_t)kvh * 524288 + (size_t)r * 128 + 2 * pp;
    Kf[kfi] = (h16)k0; Kf[kfi + 1] = (h16)k1;
    h16 h0 = (h16)v0, h1 = (h16)v1;
    vtile[rr][2 * pp] = __builtin_bit_cast(u16, h0);
    vtile[rr][2 * pp + 1] = __builtin_bit_cast(u16, h1);
  }
  __syncthreads();
#pragma unroll
  for (int it = 0; it < 4; ++it) {
    int c = tid + 256 * it;
    int d = c >> 3, rg = c & 7;
    u16 tmp[8];
#pragma unroll
    for (int u = 0; u < 8; u++) tmp[u] = vtile[rg * 8 + u][d];
    *(uint4*)((u16*)Vt + (size_t)kvh * 524288 + (size_t)d * 4096 + r0 + rg * 8) =
        *(uint4*)tmp;
  }
}

// ---------------- flash attention v3: 512 thr, QBLK=256, 3-buf, in-reg P ----------
__global__ __launch_bounds__(512, 2) void attn_k(
    const h16* __restrict__ Q, const h16* __restrict__ Kf,
    const h16* __restrict__ Vt, h16* __restrict__ O) {
  __shared__ u16 skv[3][16384];  // per buf: K[64 j][128 d] @0, V[128 d][64 j] @16KB
  const int qt = blockIdx.x, h = blockIdx.y;
  const int q0 = qt << 8, kvh = h >> 2;
  const int tid = threadIdx.x, w = tid >> 6, lane = tid & 63;
  const int lq = lane & 31, lh = lane >> 5;
  const h16* Kb = Kf + (size_t)kvh * 524288;
  const h16* Vb = Vt + (size_t)kvh * 524288;
  const int qg = q0 + w * 32 + lq;

  h16x8 qv[8];
  {
    const h16* qp = Q + (size_t)qg * 4096 + h * 128 + (lh << 3);
#pragma unroll
    for (int c = 0; c < 8; c++) qv[c] = *(const h16x8*)(qp + c * 16);
  }
  f32x16 oa[4];
#pragma unroll
  for (int d = 0; d < 4; d++)
#pragma unroll
    for (int v = 0; v < 16; v++) oa[d][v] = 0.f;
  float m2 = -3e38f, l2 = 0.f;
  const int ntiles = 36 + 4 * qt;
  const float sc = 0.08838834764831845f;

  // staging sources (512 threads, 2 K-loads + 2 V-loads per tile)
  const int jK = tid >> 4, kchK = tid & 15;
  const h16* gK = Kb + (size_t)jK * 128 + ((kchK ^ (jK & 15)) << 3);
  const int dV = tid >> 3, jchV = tid & 7;
  const h16* gV = Vb + (size_t)dV * 4096 + ((jchV ^ (dV & 7)) << 3);

  auto issueK = [&](int jt) {
    char* base = (char*)skv[jt % 3];
    const h16* s = gK + (jt << 6) * 128;
    ldscp16(s, base + tid * 16);
    ldscp16(s + 32 * 128, base + tid * 16 + 8192);
  };
  auto issueV = [&](int jt) {
    char* base = (char*)skv[jt % 3];
    const h16* s = gV + (jt << 6);
    ldscp16(s, base + 16384 + tid * 16);
    ldscp16(s + (size_t)64 * 4096, base + 16384 + tid * 16 + 8192);
  };

  issueK(0); issueV(0); issueK(1); issueV(1);
  VMCNT(4);
  SBAR();

  for (int jt = 0; jt < ntiles; ++jt) {
    const char* bp = (const char*)skv[jt % 3];
    const bool more = (jt + 2 < ntiles);
    if (more) issueK(jt + 2);
    // QK^T swapped: S^T = K x Q
    f32x16 st[2];
#pragma unroll
    for (int jb = 0; jb < 2; jb++) {
      f32x16 s;
#pragma unroll
      for (int v = 0; v < 16; v++) s[v] = 0.f;
      const int jr = jb * 32 + lq;
      __builtin_amdgcn_s_setprio(1);
#pragma unroll
      for (int kc = 0; kc < 8; kc++) {
        h16x8 ak =
            *(const h16x8*)(bp + jr * 256 + ((((kc << 1) + lh) ^ (jr & 15)) << 4));
        s = mfma32(ak, qv[kc], s);
      }
      __builtin_amdgcn_s_setprio(0);
      st[jb] = s;
    }
    if (more) issueV(jt + 2);
    // scale + mask + row max
    const int j0 = jt << 6;
    const bool domask = (jt >= ntiles - 4);
    float pm = -3e38f;
#pragma unroll
    for (int jb = 0; jb < 2; jb++)
#pragma unroll
      for (int v = 0; v < 16; v++) {
        float val = st[jb][v] * sc;
        if (domask) {
          int j = j0 + jb * 32 + (v & 3) + (((v >> 2) & 3) << 3) + (lh << 2);
          if (j > 2048 + qg) val = -1e30f;
        }
        st[jb][v] = val;
        pm = fmaxf(pm, val);
      }
    pm = fmaxf(pm, __shfl_xor(pm, 32, 64));
    if (__any(pm - m2 > 8.f)) {  // defer-max
      float mn = fmaxf(m2, pm);
      float al = __expf(m2 - mn);
      m2 = mn;
      l2 *= al;
#pragma unroll
      for (int d = 0; d < 4; d++) oa[d] *= al;
    }
    float rs = 0.f;
#pragma unroll
    for (int jb = 0; jb < 2; jb++)
#pragma unroll
      for (int v = 0; v < 16; v++) {
        float p = __expf(st[jb][v] - m2);
        st[jb][v] = p;
        rs += p;
      }
    rs += __shfl_xor(rs, 32, 64);
    l2 += rs;
    // P -> PV B-fragments in-register: quad (jb=kc>>1, c) j-start = 32jb+8c+4lh.
    // pb[kc] = P[q=lq][16kc+8lh .. +8): keep quad c=cb+lh, recv partner quad c=cb+1-lh.
    h16x8 pb[4];
#pragma unroll
    for (int kc = 0; kc < 4; kc++) {
      const int jb = kc >> 1, cb = (kc & 1) << 1;
      const int cs = cb + 1 - lh, ck = cb + lh;
      h16x4 sq, kq;
#pragma unroll
      for (int i = 0; i < 4; i++) {
        sq[i] = (h16)st[jb][(cs << 2) + i];
        kq[i] = (h16)st[jb][(ck << 2) + i];
      }
      u64 rv = __shfl_xor(__builtin_bit_cast(u64, sq), 32, 64);
      h16x4 rq = __builtin_bit_cast(h16x4, rv);
      h16x4 lo = lh ? rq : kq;
      h16x4 hi = lh ? kq : rq;
#pragma unroll
      for (int i = 0; i < 4; i++) {
        pb[kc][i] = lo[i];
        pb[kc][i + 4] = hi[i];
      }
    }
    // PV: O^T = V^T x P^T
    __builtin_amdgcn_s_setprio(1);
#pragma unroll
    for (int d = 0; d < 4; d++) {
      const int dr = (d << 5) + lq;
#pragma unroll
      for (int kc = 0; kc < 4; kc++) {
        h16x8 av = *(const h16x8*)(bp + 16384 + dr * 128 +
                                   ((((kc << 1) + lh) ^ (dr & 7)) << 4));
        oa[d] = mfma32(av, pb[kc], oa[d]);
      }
    }
    __builtin_amdgcn_s_setprio(0);
    if (jt + 1 < ntiles) {
      if (more) VMCNT(4);
      else VMCNT(0);
      SBAR();
    }
  }
  float rl = 1.f / l2;
  h16* Op = O + (size_t)qg * 4096 + h * 128;
#pragma unroll
  for (int d = 0; d < 4; d++)
#pragma unroll
    for (int b = 0; b < 4; b++) {
      h16x4 ov;
#pragma unroll
      for (int i = 0; i < 4; i++) ov[i] = (h16)(oa[d][(b << 2) + i] * rl);
      *(h16x4*)(Op + (d << 5) + (b << 3) + (lh << 2)) = ov;
    }
}

extern "C" void kernel_launch(void* const* d_in, const int* in_sizes, int n_in,
                              void* d_out, int out_size, void* d_ws, size_t ws_size,
                              hipStream_t stream) {
  const float* x = (const float*)d_in[0];
  const float* freqs = (const float*)d_in[2];
  const float* oldK = (const float*)d_in[3];
  const float* oldV = (const float*)d_in[4];
  const float* wq = (const float*)d_in[5];
  const float* wk = (const float*)d_in[6];
  const float* wvp = (const float*)d_in[7];
  const float* wo = (const float*)d_in[8];
  const float* w1 = (const float*)d_in[9];
  const float* w2 = (const float*)d_in[10];
  const float* w3 = (const float*)d_in[11];
  const float* anw = (const float*)d_in[12];
  const float* fnw = (const float*)d_in[13];
  float* out = (float*)d_out;
  float* outK = out + 8388608;
  float* outV = out + 12582912;

  char* ws = (char*)d_ws;
  // layout, peak 160 MiB (proven-safe)
  h16* xn = (h16*)(ws + 0);                // 16.78 MB f16 [2048][4096]
  h16* bufW = (h16*)(ws + 16777216);       // 58.72 MB tiled f16 weights (reused)
  float* hbuf = (float*)(ws + 75497472);   // 33.55 MB f32 [2048][4096]
  float* kvraw = (float*)(ws + 75497472);  // 16.78 MB f32 [2048][2048] (aliased)
  h16* kf = (h16*)(ws + 92274688);         //  8.39 MB
  h16* vt = (h16*)(ws + 100663296);        //  8.39 MB
  h16* ub = (h16*)(ws + 109051904);        // 58.72 MB f16 [2048][14336]
  h16* qraw = (h16*)(ws + 109051904);      // 16.78 MB (aliased in ub span)
  h16* attnb = (h16*)(ws + 125829120);     // 16.78 MB (aliased in ub span)

  // attention path
  rmsnorm_k<<<2048, 256, 0, stream>>>(x, anw, xn);
  convw_k<<<dim3(32, 64), 256, 0, stream>>>(wq, bufW, 4096, 64);
  convw_k<<<dim3(8, 64), 256, 0, stream>>>(wk, bufW + ((size_t)32 * 64 << 13), 1024, 64);
  convw_k<<<dim3(8, 64), 256, 0, stream>>>(wvp, bufW + ((size_t)40 * 64 << 13), 1024, 64);
  gemm_k<5><<<dim3(24, 16), 512, 0, stream>>>(xn, bufW, kvraw, qraw, nullptr,
                                              nullptr, 4096, 4096, 0, 0);
  rope_q_k<<<2048, 256, 0, stream>>>(qraw, freqs, qraw);
  cache_build_k<<<dim3(64, 8), 256, 0, stream>>>(oldK, oldV, kvraw, freqs, outK,
                                                 outV, kf, vt);
  attn_k<<<dim3(8, 32), 512, 0, stream>>>(qraw, kf, vt, attnb);
  convw_k<<<dim3(32, 64), 256, 0, stream>>>(wo, bufW, 4096, 64);
  gemm_k<2><<<dim3(16, 16), 512, 0, stream>>>(attnb, bufW, hbuf, nullptr, x,
                                              nullptr, 4096, 4096, 4096, 0);
  // FFN path
  rmsnorm_k<<<2048, 256, 0, stream>>>(hbuf, fnw, xn);
  convw_k<<<dim3(56, 64), 256, 0, stream>>>(w1, bufW, 14336, 64);
  gemm_k<1><<<dim3(28, 16), 512, 0, stream>>>(xn, bufW, nullptr, ub, nullptr,
                                              nullptr, 4096, 4096, 14336, 0);
  convw_k<<<dim3(56, 64), 256, 0, stream>>>(w1 + 7168, bufW, 14336, 64);
  gemm_k<1><<<dim3(28, 16), 512, 0, stream>>>(xn, bufW, nullptr, ub, nullptr,
                                              nullptr, 4096, 4096, 14336, 7168);
  convw_k<<<dim3(56, 64), 256, 0, stream>>>(w3, bufW, 14336, 64);
  gemm_k<3><<<dim3(28, 16), 512, 0, stream>>>(xn, bufW, nullptr, ub, nullptr, ub,
                                              4096, 4096, 14336, 0);
  convw_k<<<dim3(56, 64), 256, 0, stream>>>(w3 + 7168, bufW, 14336, 64);
  gemm_k<3><<<dim3(28, 16), 512, 0, stream>>>(xn, bufW, nullptr, ub, nullptr, ub,
                                              4096, 4096, 14336, 7168);
  convw_k<<<dim3(32, 112), 256, 0, stream>>>(w2, bufW, 4096, 112);
  gemm_k<2><<<dim3(16, 16), 512, 0, stream>>>(ub, bufW, out, nullptr, hbuf,
                                              nullptr, 7168, 14336, 4096, 0);
  convw_k<<<dim3(32, 112), 256, 0, stream>>>(w2 + (size_t)7168 * 4096, bufW, 4096, 112);
  gemm_k<4><<<dim3(16, 16), 512, 0, stream>>>(ub + 7168, bufW, out, nullptr,
                                              nullptr, nullptr, 7168, 14336, 4096, 0);
}

// Round 10
// 1532.967 us; speedup vs baseline: 3.6527x; 1.1158x over previous
//
#include <hip/hip_runtime.h>

typedef _Float16 h16;
typedef _Float16 h16x4 __attribute__((ext_vector_type(4)));
typedef _Float16 h16x8 __attribute__((ext_vector_type(8)));
typedef __fp16 fp16x2 __attribute__((ext_vector_type(2)));
typedef float f32x4 __attribute__((ext_vector_type(4)));
typedef float f32x16 __attribute__((ext_vector_type(16)));
typedef unsigned short u16;
typedef unsigned int u32;
typedef unsigned int u32x4 __attribute__((ext_vector_type(4)));

__device__ __forceinline__ f32x4 mfma16(h16x8 a, h16x8 b, f32x4 c) {
  return __builtin_amdgcn_mfma_f32_16x16x32_f16(a, b, c, 0, 0, 0);
}
__device__ __forceinline__ f32x16 mfma32(h16x8 a, h16x8 b, f32x16 c) {
  return __builtin_amdgcn_mfma_f32_32x32x16_f16(a, b, c, 0, 0, 0);
}
__device__ __forceinline__ float fexp2(float x) {
#if __has_builtin(__builtin_amdgcn_exp2f)
  return __builtin_amdgcn_exp2f(x);
#else
  return exp2f(x);
#endif
}
__device__ __forceinline__ u32 pkh(float a, float b) {
  fp16x2 t = __builtin_amdgcn_cvt_pkrtz(a, b);
  return __builtin_bit_cast(u32, t);
}

typedef const __attribute__((address_space(1))) void* gas_p;
typedef __attribute__((address_space(3))) void* las_p;
__device__ __forceinline__ void ldscp16(const void* g, void* l) {
  __builtin_amdgcn_global_load_lds((gas_p)g, (las_p)l, 16, 0, 0);
}
#define VMCNT(n) asm volatile("s_waitcnt vmcnt(" #n ")" ::: "memory")
#define SBAR() asm volatile("s_barrier" ::: "memory")

// ---------------- RMSNorm: f32 [2048][4096] -> f16 ----------------
__global__ __launch_bounds__(256) void rmsnorm_k(
    const float* __restrict__ x, const float* __restrict__ w, h16* __restrict__ out) {
  const int row = blockIdx.x, t = threadIdx.x;
  const float* xr = x + (size_t)row * 4096;
  float4 v[4];
  float ss = 0.f;
#pragma unroll
  for (int j = 0; j < 4; j++) {
    v[j] = *(const float4*)(xr + 4 * t + 1024 * j);
    ss += v[j].x * v[j].x + v[j].y * v[j].y + v[j].z * v[j].z + v[j].w * v[j].w;
  }
#pragma unroll
  for (int off = 1; off < 64; off <<= 1) ss += __shfl_xor(ss, off, 64);
  __shared__ float red[4];
  if ((t & 63) == 0) red[t >> 6] = ss;
  __syncthreads();
  float scale = rsqrtf((red[0] + red[1] + red[2] + red[3]) * (1.f / 4096.f) + 1e-6f);
  h16* orow = out + (size_t)row * 4096;
#pragma unroll
  for (int j = 0; j < 4; j++) {
    float4 wv = *(const float4*)(w + 4 * t + 1024 * j);
    h16x4 o;
    o[0] = (h16)(v[j].x * scale * wv.x);
    o[1] = (h16)(v[j].y * scale * wv.y);
    o[2] = (h16)(v[j].z * scale * wv.z);
    o[3] = (h16)(v[j].w * scale * wv.w);
    *(h16x4*)(orow + 4 * t + 1024 * j) = o;
  }
}

// ------- weight convert: f32 -> f16 tiled+swizzled LDS images -------
__global__ __launch_bounds__(256) void convw_k(
    const float* __restrict__ W, h16* __restrict__ out, int rowN, int ktiles) {
  __shared__ u16 timg[8192];
  const int t = threadIdx.x, b = blockIdx.x, kt = blockIdx.y;
  const float* src = W + (size_t)(kt * 64) * rowN + b * 128;
#pragma unroll
  for (int i = 0; i < 8; i++) {
    int c = t + (i << 8);
    int krow = c >> 5, nc = (c & 31) << 2;
    float4 v = *(const float4*)(src + (size_t)krow * rowN + nc);
    int kc = krow >> 3, e = krow & 7;
    float vals[4] = {v.x, v.y, v.z, v.w};
#pragma unroll
    for (int j = 0; j < 4; j++) {
      int m = nc + j;
      h16 hv = (h16)vals[j];
      timg[(m << 6) + ((kc ^ (m & 7)) << 3) + e] = __builtin_bit_cast(u16, hv);
    }
  }
  __syncthreads();
  uint4* dst = (uint4*)(out + ((size_t)(b * ktiles + kt) << 13));
  const uint4* s4 = (const uint4*)timg;
#pragma unroll
  for (int i = 0; i < 4; i++) dst[t + (i << 8)] = s4[t + (i << 8)];
}

// ---------------- GEMM: 512 thr, BM=128 BN=256 BK=64, 3-buf counted pipeline --------
// EPI: 1 f16; 2 f32=resid+acc; 3 f16=silu(uin)*acc; 4 f32+=acc;
//      5 split: col<4096 -> f16 qraw, else f32 kvraw (col-4096, ld 2048)
template <int EPI>
__global__ __launch_bounds__(512, 2) void gemm_k(
    const h16* __restrict__ A, const h16* __restrict__ Wt,
    float* outF, h16* outH, const float* resid, const h16* uin,
    int K, int lda, int ldo, int no0) {
  __shared__ u16 lds[3][24576];
  const int tid = threadIdx.x, lane = tid & 63;
  const int wv = tid >> 6, wr = wv >> 2, wc = wv & 3;
  const int g = lane >> 4, lr = lane & 15;
  const int m0 = blockIdx.y << 7, n0 = blockIdx.x << 8;
  const int ktiles = K >> 6;

  f32x4 acc[4][4];
#pragma unroll
  for (int i = 0; i < 4; i++)
#pragma unroll
    for (int j = 0; j < 4; j++) acc[i][j] = {0.f, 0.f, 0.f, 0.f};

  const int rA = tid >> 3;
  const int kcA = (tid & 7) ^ (rA & 7);
  const h16* gA = A + (size_t)(m0 + rA) * lda + (kcA << 3);
  const h16* gA2 = gA + (size_t)64 * lda;
  const h16* gB0 = Wt + (((size_t)(2 * blockIdx.x) * ktiles) << 13) + tid * 8;
  const h16* gB1 = Wt + (((size_t)(2 * blockIdx.x + 1) * ktiles) << 13) + tid * 8;

  auto issueA = [&](int t) {
    char* base = (char*)lds[t % 3];
    ldscp16(gA + t * 64, base + tid * 16);
    ldscp16(gA2 + t * 64, base + tid * 16 + 8192);
    ldscp16(gB0 + ((size_t)t << 13), base + 16384 + tid * 16);
    ldscp16(gB0 + ((size_t)t << 13) + 4096, base + 16384 + tid * 16 + 8192);
  };
  auto issueB = [&](int t) {
    char* base = (char*)lds[t % 3];
    ldscp16(gB1 + ((size_t)t << 13), base + 32768 + tid * 16);
    ldscp16(gB1 + ((size_t)t << 13) + 4096, base + 32768 + tid * 16 + 8192);
  };

  issueA(0); issueB(0); issueA(1); issueB(1);
  VMCNT(6);
  SBAR();

  for (int t = 0; t < ktiles; ++t) {
    const char* bp = (const char*)lds[t % 3];
    const bool more = (t + 2 < ktiles);
#pragma unroll
    for (int ks = 0; ks < 2; ++ks) {
      h16x8 av[4], bv[4];
      const int cc = (ks << 2) + g;
#pragma unroll
      for (int f = 0; f < 4; f++) {
        int row = (wr << 6) + (f << 4) + lr;
        av[f] = *(const h16x8*)(bp + row * 128 + ((cc ^ (row & 7)) << 4));
        int nr = (wc << 6) + (f << 4) + lr;
        bv[f] = *(const h16x8*)(bp + 16384 + nr * 128 + ((cc ^ (nr & 7)) << 4));
      }
      if (more) {
        if (ks == 0) issueA(t + 2);
        else issueB(t + 2);
      }
      __builtin_amdgcn_s_setprio(1);
#pragma unroll
      for (int fi = 0; fi < 4; fi++)
#pragma unroll
        for (int fj = 0; fj < 4; fj++)
          acc[fi][fj] = mfma16(av[fi], bv[fj], acc[fi][fj]);
      __builtin_amdgcn_s_setprio(0);
    }
    if (t + 1 < ktiles) {
      if (more) VMCNT(6);
      else VMCNT(0);
      SBAR();
    }
  }
#pragma unroll
  for (int fi = 0; fi < 4; fi++) {
    const int row = m0 + (wr << 6) + (fi << 4) + (g << 2);
#pragma unroll
    for (int fj = 0; fj < 4; fj++) {
      const int col = no0 + n0 + (wc << 6) + (fj << 4) + lr;
#pragma unroll
      for (int r = 0; r < 4; r++) {
        float vl = acc[fi][fj][r];
        if constexpr (EPI == 5) {
          if (col < 4096) outH[(size_t)(row + r) * 4096 + col] = (h16)vl;
          else outF[(size_t)(row + r) * 2048 + (col - 4096)] = vl;
        } else {
          size_t idx = (size_t)(row + r) * ldo + col;
          if constexpr (EPI == 1) outH[idx] = (h16)vl;
          else if constexpr (EPI == 2) outF[idx] = resid[idx] + vl;
          else if constexpr (EPI == 3) {
            float u = (float)uin[idx];
            outH[idx] = (h16)((u / (1.f + __expf(-u))) * vl);
          } else outF[idx] = outF[idx] + vl;
        }
      }
    }
  }
}

// ---------------- RoPE on Q (f16, in-place safe), folds softmax scale ----------
// SCL = 1/sqrt(128) * log2(e) so attn exp becomes raw exp2
__global__ __launch_bounds__(256) void rope_q_k(
    const h16* __restrict__ qin, const float* __restrict__ freqs, h16* qout) {
  const int row = blockIdx.x, t = threadIdx.x;
  const float SCL = 0.12751743647239037f;
#pragma unroll
  for (int it = 0; it < 8; ++it) {
    int pid = t + 256 * it;
    int head = pid >> 6, pp = pid & 63;
    size_t idx = (size_t)row * 4096 + head * 128 + 2 * pp;
    float x0 = (float)qin[idx], x1 = (float)qin[idx + 1];
    float cs = freqs[row * 128 + 2 * pp], sn = freqs[row * 128 + 2 * pp + 1];
    qout[idx] = (h16)((x0 * cs - x1 * sn) * SCL);
    qout[idx + 1] = (h16)((x0 * sn + x1 * cs) * SCL);
  }
}

// ------- build new cache: f32 outs + f16 K [kvh][r][d] + f16 V^T [kvh][d][r] -------
__global__ __launch_bounds__(256) void cache_build_k(
    const float* __restrict__ oldK, const float* __restrict__ oldV,
    const float* __restrict__ kvraw, const float* __restrict__ freqs,
    float* __restrict__ outK, float* __restrict__ outV,
    h16* __restrict__ Kf, h16* __restrict__ Vt) {
  const int rt = blockIdx.x, kvh = blockIdx.y;
  const int r0 = rt * 64, tid = threadIdx.x;
  __shared__ u16 vtile[64][128];
#pragma unroll
  for (int it = 0; it < 16; ++it) {
    int s = tid + 256 * it;
    int rr = s >> 6, pp = s & 63;
    int r = r0 + rr;
    float k0, k1, v0, v1;
    if (r < 2048) {
      const float* kp = oldK + (size_t)(r + 2048) * 1024 + kvh * 128 + 2 * pp;
      k0 = kp[0]; k1 = kp[1];
      const float* vp = oldV + (size_t)(r + 2048) * 1024 + kvh * 128 + 2 * pp;
      v0 = vp[0]; v1 = vp[1];
    } else {
      int tpos = r - 2048;
      const float* kp = kvraw + (size_t)tpos * 2048 + kvh * 128 + 2 * pp;
      float x0 = kp[0], x1 = kp[1];
      float cs = freqs[tpos * 128 + 2 * pp], sn = freqs[tpos * 128 + 2 * pp + 1];
      k0 = x0 * cs - x1 * sn;
      k1 = x0 * sn + x1 * cs;
      const float* vp = kvraw + (size_t)tpos * 2048 + 1024 + kvh * 128 + 2 * pp;
      v0 = vp[0]; v1 = vp[1];
    }
    size_t oidx = (size_t)r * 1024 + kvh * 128 + 2 * pp;
    outK[oidx] = k0; outK[oidx + 1] = k1;
    outV[oidx] = v0; outV[oidx + 1] = v1;
    size_t kfi = (size_t)kvh * 524288 + (size_t)r * 128 + 2 * pp;
    Kf[kfi] = (h16)k0; Kf[kfi + 1] = (h16)k1;
    h16 h0 = (h16)v0, h1 = (h16)v1;
    vtile[rr][2 * pp] = __builtin_bit_cast(u16, h0);
    vtile[rr][2 * pp + 1] = __builtin_bit_cast(u16, h1);
  }
  __syncthreads();
#pragma unroll
  for (int it = 0; it < 4; ++it) {
    int c = tid + 256 * it;
    int d = c >> 3, rg = c & 7;
    u16 tmp[8];
#pragma unroll
    for (int u = 0; u < 8; u++) tmp[u] = vtile[rg * 8 + u][d];
    *(uint4*)((u16*)Vt + (size_t)kvh * 524288 + (size_t)d * 4096 + r0 + rg * 8) =
        *(uint4*)tmp;
  }
}

// -------- flash attention v4: 256 thr, QBLK=128, 2-buf, lean softmax --------
__global__ __launch_bounds__(256, 2) void attn_k(
    const h16* __restrict__ Q, const h16* __restrict__ Kf,
    const h16* __restrict__ Vt, h16* __restrict__ O) {
  __shared__ u16 skv[2][16384];  // per buf: K[64 j][128 d] @0, V[128 d][64 j] @16KB
  const int qt = 15 - blockIdx.x, h = blockIdx.y;
  const int q0 = qt << 7, kvh = h >> 2;
  const int tid = threadIdx.x, w = tid >> 6, lane = tid & 63;
  const int lq = lane & 31, lh = lane >> 5;
  const h16* Kb = Kf + (size_t)kvh * 524288;
  const h16* Vb = Vt + (size_t)kvh * 524288;
  const int qg = q0 + w * 32 + lq;

  h16x8 qv[8];
  {
    const h16* qp = Q + (size_t)qg * 4096 + h * 128 + (lh << 3);
#pragma unroll
    for (int c = 0; c < 8; c++) qv[c] = *(const h16x8*)(qp + c * 16);
  }
  h16x8 hone;
#pragma unroll
  for (int i = 0; i < 8; i++) hone[i] = (h16)1.0f;
  f32x16 oa[4], ol2;
#pragma unroll
  for (int d = 0; d < 4; d++)
#pragma unroll
    for (int v = 0; v < 16; v++) oa[d][v] = 0.f;
#pragma unroll
  for (int v = 0; v < 16; v++) ol2[v] = 0.f;
  float m2 = -3e38f;
  const int ntiles = 34 + 2 * qt;

  // staging (256 thr: 4 K-loads + 4 V-loads per tile per thread)
  const int jK = tid >> 4, kch = tid & 15;
  const h16* gK = Kb + (size_t)jK * 128 + ((kch ^ (jK & 15)) << 3);
  const int dV = tid >> 3, jch = tid & 7;
  const h16* gV = Vb + (size_t)dV * 4096 + ((jch ^ (dV & 7)) << 3);

  auto issueK = [&](int jt) {
    char* base = (char*)skv[jt & 1];
    const h16* s = gK + (size_t)(jt << 6) * 128;
#pragma unroll
    for (int i = 0; i < 4; i++)
      ldscp16(s + (size_t)i * 2048, base + tid * 16 + i * 4096);
  };
  auto issueV = [&](int jt) {
    char* base = (char*)skv[jt & 1] + 16384;
    const h16* s = gV + (jt << 6);
#pragma unroll
    for (int i = 0; i < 4; i++)
      ldscp16(s + (size_t)i * 131072, base + tid * 16 + i * 4096);
  };

  issueK(0); issueV(0);
  VMCNT(0);
  SBAR();

  for (int jt = 0; jt < ntiles; ++jt) {
    const char* bp = (const char*)skv[jt & 1];
    const bool more = (jt + 1 < ntiles);
    if (more) issueK(jt + 1);
    // QK^T swapped: S^T = K x Q (st already scaled by 1/sqrt(d)*log2e via Q)
    f32x16 st[2];
#pragma unroll
    for (int jb = 0; jb < 2; jb++) {
      f32x16 s;
#pragma unroll
      for (int v = 0; v < 16; v++) s[v] = 0.f;
      const int jr = jb * 32 + lq;
      __builtin_amdgcn_s_setprio(1);
#pragma unroll
      for (int kc = 0; kc < 8; kc++) {
        h16x8 ak =
            *(const h16x8*)(bp + jr * 256 + ((((kc << 1) + lh) ^ (jr & 15)) << 4));
        s = mfma32(ak, qv[kc], s);
      }
      __builtin_amdgcn_s_setprio(0);
      st[jb] = s;
    }
    if (more) issueV(jt + 1);
    // mask (last 2 tiles only)
    if (jt >= ntiles - 2) {
      const int j0 = jt << 6;
#pragma unroll
      for (int jb = 0; jb < 2; jb++)
#pragma unroll
        for (int v = 0; v < 16; v++) {
          int j = j0 + jb * 32 + (v & 3) + (((v >> 2) & 3) << 3) + (lh << 2);
          if (j > 2048 + qg) st[jb][v] = -1e30f;
        }
    }
    // row max (tree, max3-fused)
    float pm = fmaxf(st[0][0], st[0][1]);
#pragma unroll
    for (int v = 2; v < 16; v += 2) pm = fmaxf(fmaxf(st[0][v], st[0][v + 1]), pm);
#pragma unroll
    for (int v = 0; v < 16; v += 2) pm = fmaxf(fmaxf(st[1][v], st[1][v + 1]), pm);
    pm = fmaxf(pm, __shfl_xor(pm, 32, 64));
    if (__any(pm - m2 > 8.f)) {  // defer-max (log2 units)
      float mn = fmaxf(m2, pm);
      float al = fexp2(m2 - mn);
      m2 = mn;
#pragma unroll
      for (int d = 0; d < 4; d++) oa[d] *= al;
      ol2 *= al;
    }
    // p = exp2(st - m2), pack to f16 pairs
    u32 pw[2][8];
#pragma unroll
    for (int jb = 0; jb < 2; jb++)
#pragma unroll
      for (int c = 0; c < 4; c++) {
        float p0 = fexp2(st[jb][4 * c] - m2);
        float p1 = fexp2(st[jb][4 * c + 1] - m2);
        float p2 = fexp2(st[jb][4 * c + 2] - m2);
        float p3 = fexp2(st[jb][4 * c + 3] - m2);
        pw[jb][2 * c] = pkh(p0, p1);
        pw[jb][2 * c + 1] = pkh(p2, p3);
      }
    // redistribute quads across lane^32 -> PV B-fragments
    h16x8 pb[4];
#pragma unroll
    for (int kc = 0; kc < 4; kc++) {
      const int jb = kc >> 1, cb = (kc & 1) << 1;
      u32 oa_ = pw[jb][2 * cb], ob_ = pw[jb][2 * cb + 1];
      u32 oc_ = pw[jb][2 * cb + 2], od_ = pw[jb][2 * cb + 3];
      u32 s0 = lh ? oa_ : oc_, s1 = lh ? ob_ : od_;
      u32 r0 = __shfl_xor(s0, 32, 64), r1 = __shfl_xor(s1, 32, 64);
      u32x4 wds = {lh ? r0 : oa_, lh ? r1 : ob_, lh ? oc_ : r0, lh ? od_ : r1};
      pb[kc] = __builtin_bit_cast(h16x8, wds);
    }
    // PV: O^T = V^T x P^T ; l2 via ones-MFMA
    __builtin_amdgcn_s_setprio(1);
#pragma unroll
    for (int d = 0; d < 4; d++) {
      const int dr = (d << 5) + lq;
#pragma unroll
      for (int kc = 0; kc < 4; kc++) {
        h16x8 av = *(const h16x8*)(bp + 16384 + dr * 128 +
                                   ((((kc << 1) + lh) ^ (dr & 7)) << 4));
        oa[d] = mfma32(av, pb[kc], oa[d]);
      }
    }
#pragma unroll
    for (int kc = 0; kc < 4; kc++) ol2 = mfma32(hone, pb[kc], ol2);
    __builtin_amdgcn_s_setprio(0);
    if (more) {
      VMCNT(0);
      SBAR();
    }
  }
  float rl = 1.f / ol2[0];
  h16* Op = O + (size_t)qg * 4096 + h * 128;
#pragma unroll
  for (int d = 0; d < 4; d++)
#pragma unroll
    for (int b = 0; b < 4; b++) {
      h16x4 ov;
#pragma unroll
      for (int i = 0; i < 4; i++) ov[i] = (h16)(oa[d][(b << 2) + i] * rl);
      *(h16x4*)(Op + (d << 5) + (b << 3) + (lh << 2)) = ov;
    }
}

extern "C" void kernel_launch(void* const* d_in, const int* in_sizes, int n_in,
                              void* d_out, int out_size, void* d_ws, size_t ws_size,
                              hipStream_t stream) {
  const float* x = (const float*)d_in[0];
  const float* freqs = (const float*)d_in[2];
  const float* oldK = (const float*)d_in[3];
  const float* oldV = (const float*)d_in[4];
  const float* wq = (const float*)d_in[5];
  const float* wk = (const float*)d_in[6];
  const float* wvp = (const float*)d_in[7];
  const float* wo = (const float*)d_in[8];
  const float* w1 = (const float*)d_in[9];
  const float* w2 = (const float*)d_in[10];
  const float* w3 = (const float*)d_in[11];
  const float* anw = (const float*)d_in[12];
  const float* fnw = (const float*)d_in[13];
  float* out = (float*)d_out;
  float* outK = out + 8388608;
  float* outV = out + 12582912;

  char* ws = (char*)d_ws;
  h16* xn = (h16*)(ws + 0);                // 16.78 MB f16 [2048][4096]
  h16* bufW = (h16*)(ws + 16777216);       // 58.72 MB tiled f16 weights (reused)
  float* hbuf = (float*)(ws + 75497472);   // 33.55 MB f32 [2048][4096]
  float* kvraw = (float*)(ws + 75497472);  // 16.78 MB f32 [2048][2048] (aliased)
  h16* kf = (h16*)(ws + 92274688);         //  8.39 MB
  h16* vt = (h16*)(ws + 100663296);        //  8.39 MB
  h16* ub = (h16*)(ws + 109051904);        // 58.72 MB f16 [2048][14336]
  h16* qraw = (h16*)(ws + 109051904);      // 16.78 MB (aliased in ub span)
  h16* attnb = (h16*)(ws + 125829120);     // 16.78 MB (aliased in ub span)

  // attention path
  rmsnorm_k<<<2048, 256, 0, stream>>>(x, anw, xn);
  convw_k<<<dim3(32, 64), 256, 0, stream>>>(wq, bufW, 4096, 64);
  convw_k<<<dim3(8, 64), 256, 0, stream>>>(wk, bufW + ((size_t)32 * 64 << 13), 1024, 64);
  convw_k<<<dim3(8, 64), 256, 0, stream>>>(wvp, bufW + ((size_t)40 * 64 << 13), 1024, 64);
  gemm_k<5><<<dim3(24, 16), 512, 0, stream>>>(xn, bufW, kvraw, qraw, nullptr,
                                              nullptr, 4096, 4096, 0, 0);
  rope_q_k<<<2048, 256, 0, stream>>>(qraw, freqs, qraw);
  cache_build_k<<<dim3(64, 8), 256, 0, stream>>>(oldK, oldV, kvraw, freqs, outK,
                                                 outV, kf, vt);
  attn_k<<<dim3(16, 32), 256, 0, stream>>>(qraw, kf, vt, attnb);
  convw_k<<<dim3(32, 64), 256, 0, stream>>>(wo, bufW, 4096, 64);
  gemm_k<2><<<dim3(16, 16), 512, 0, stream>>>(attnb, bufW, hbuf, nullptr, x,
                                              nullptr, 4096, 4096, 4096, 0);
  // FFN path
  rmsnorm_k<<<2048, 256, 0, stream>>>(hbuf, fnw, xn);
  convw_k<<<dim3(56, 64), 256, 0, stream>>>(w1, bufW, 14336, 64);
  gemm_k<1><<<dim3(28, 16), 512, 0, stream>>>(xn, bufW, nullptr, ub, nullptr,
                                              nullptr, 4096, 4096, 14336, 0);
  convw_k<<<dim3(56, 64), 256, 0, stream>>>(w1 + 7168, bufW, 14336, 64);
  gemm_k<1><<<dim3(28, 16), 512, 0, stream>>>(xn, bufW, nullptr, ub, nullptr,
                                              nullptr, 4096, 4096, 14336, 7168);
  convw_k<<<dim3(56, 64), 256, 0, stream>>>(w3, bufW, 14336, 64);
  gemm_k<3><<<dim3(28, 16), 512, 0, stream>>>(xn, bufW, nullptr, ub, nullptr, ub,
                                              4096, 4096, 14336, 0);
  convw_k<<<dim3(56, 64), 256, 0, stream>>>(w3 + 7168, bufW, 14336, 64);
  gemm_k<3><<<dim3(28, 16), 512, 0, stream>>>(xn, bufW, nullptr, ub, nullptr, ub,
                                              4096, 4096, 14336, 7168);
  convw_k<<<dim3(32, 112), 256, 0, stream>>>(w2, bufW, 4096, 112);
  gemm_k<2><<<dim3(16, 16), 512, 0, stream>>>(ub, bufW, out, nullptr, hbuf,
                                              nullptr, 7168, 14336, 4096, 0);
  convw_k<<<dim3(32, 112), 256, 0, stream>>>(w2 + (size_t)7168 * 4096, bufW, 4096, 112);
  gemm_k<4><<<dim3(16, 16), 512, 0, stream>>>(ub + 7168, bufW, out, nullptr,
                                              nullptr, nullptr, 7168, 14336, 4096, 0);
}